// Round 8
// baseline (205.693 us; speedup 1.0000x reference)
//
#include <hip/hip_runtime.h>

// ---------------------------------------------------------------------------
// MultiHeadedAttention: B=2, S=2048, Dm=1024, H=16, hd=64
// R11: uniform-makespan attention. Counter evidence (Occ 32% vs 50% resident,
// VALUBusy 40%): old decomposition wasted ~half the wave-slots on duration
// tail + inactive waves. New decomposition: each 256-thr block (4 waves)
// processes q-tile A then q-tile 31-A SEQUENTIALLY -> every block exactly
// 33 key-tile rounds, every wave active every round, all 512 blocks (2/CU)
// finish together. Inner loop pieces verbatim from R10 (verified): XOR-swz
// staging, 4-deep LDS buffers, counted vmcnt + raw barrier, QK||PV dual
// stream, ds_bpermute P-transpose, scale*log2e pre-folded into W_in.
// ---------------------------------------------------------------------------

typedef __bf16 bf16x8 __attribute__((ext_vector_type(8)));
typedef float f32x4 __attribute__((ext_vector_type(4)));
typedef int i32x4 __attribute__((ext_vector_type(4)));

#define B_   2
#define S_   2048
#define DM   1024
#define NH   16
#define HD   64
#define N3   3072
#define M_   4096   // B_*S_

// 0.125 (1/sqrt(64)) * log2(e) -- folded into W_in Q-columns on host side
#define SCALE_LOG2E 0.180336884f

__device__ __forceinline__ unsigned short f2bf(float f) {
  unsigned int u = __float_as_uint(f);
  u += 0x7fffu + ((u >> 16) & 1u);   // round-to-nearest-even
  return (unsigned short)(u >> 16);
}

__device__ __forceinline__ void gload_lds16(void* lds, const void* g) {
  __builtin_amdgcn_global_load_lds(
      (__attribute__((address_space(1))) void*)g,
      (__attribute__((address_space(3))) void*)lds, 16, 0, 0);
}

// ---------------- fp32 -> bf16 elementwise (query) -------------------------
__global__ __launch_bounds__(256) void f32_to_bf16_vec(
    const float4* __restrict__ in, unsigned short* __restrict__ out, int n4) {
  int i = blockIdx.x * 256 + threadIdx.x;
  if (i < n4) {
    float4 v = in[i];
    ushort4 o;
    o.x = f2bf(v.x); o.y = f2bf(v.y); o.z = f2bf(v.z); o.w = f2bf(v.w);
    *(ushort4*)(&out[(size_t)i * 4]) = o;
  }
}

// ------- fp32 [R][C] -> bf16 [C][R] transpose (weights), row-scaled --------
__global__ __launch_bounds__(256) void transpose_f32_bf16(
    const float* __restrict__ in, unsigned short* __restrict__ out, int R, int C,
    int scale_rows, float scale) {
  __shared__ float tile[32][33];
  const int tx = threadIdx.x, ty = threadIdx.y;
  const int x = blockIdx.x * 32 + tx;
  const int y0 = blockIdx.y * 32;
#pragma unroll
  for (int j = 0; j < 32; j += 8)
    tile[ty + j][tx] = in[(size_t)(y0 + ty + j) * C + x];
  __syncthreads();
  const int ox = y0 + tx;
  const int oy0 = blockIdx.x * 32;
#pragma unroll
  for (int j = 0; j < 32; j += 8) {
    const int orow = oy0 + ty + j;
    float v = tile[tx][ty + j];
    if (orow < scale_rows) v *= scale;
    out[(size_t)orow * R + ox] = f2bf(v);
  }
}

// ---------------- V slice of qkv -> vT[b][h][d][s] (bf16) ------------------
__global__ __launch_bounds__(256) void transpose_v(
    const unsigned short* __restrict__ qkv, unsigned short* __restrict__ vT) {
  __shared__ unsigned short tile[32][33];
  const int tx = threadIdx.x, ty = threadIdx.y;
  const int c0 = blockIdx.x * 32;   // v-dim 0..1023
  const int r0 = blockIdx.y * 32;   // token 0..4095
#pragma unroll
  for (int j = 0; j < 32; j += 8)
    tile[ty + j][tx] = qkv[(size_t)(r0 + ty + j) * N3 + 2 * DM + c0 + tx];
  __syncthreads();
  const int b = r0 >> 11;
  const int srow = (r0 & 2047);
  const int head = c0 >> 6;
#pragma unroll
  for (int j = 0; j < 32; j += 8) {
    const int d = (c0 & 63) + ty + j;
    vT[(size_t)((b * NH + head) * HD + d) * S_ + srow + tx] = tile[tx][ty + j];
  }
}

// ---------------- GEMM: C[M][N] = A[M][K] @ Bt[N][K]^T ---------------------
template <int OUT_BF16>
__global__ __launch_bounds__(256) void gemm_abt(
    const unsigned short* __restrict__ A, const unsigned short* __restrict__ Bt,
    void* __restrict__ Cv, int M, int N, int K) {
  __shared__ __align__(16) unsigned short a_sm[128 * 32];
  __shared__ __align__(16) unsigned short b_sm[128 * 32];
  const int tid = threadIdx.x;
  const int lane = tid & 63, wave = tid >> 6;
  const int quad = lane >> 4, l15 = lane & 15;
  const int row0 = blockIdx.y * 128, col0 = blockIdx.x * 128;
  const int wm = (wave >> 1) * 64, wn = (wave & 1) * 64;

  f32x4 acc[4][4];
#pragma unroll
  for (int i = 0; i < 4; i++)
#pragma unroll
    for (int j = 0; j < 4; j++) acc[i][j] = (f32x4){0.f, 0.f, 0.f, 0.f};

  const int e0 = tid * 8;

  for (int k0 = 0; k0 < K; k0 += 32) {
    __syncthreads();
#pragma unroll
    for (int i = 0; i < 2; i++) {
      int e = e0 + i * 2048;
      int r = e >> 5, c = e & 31;
      gload_lds16(&a_sm[e], &A[(size_t)(row0 + r) * K + k0 + c]);
      gload_lds16(&b_sm[e], &Bt[(size_t)(col0 + r) * K + k0 + c]);
    }
    __syncthreads();

    bf16x8 af[4], bfb[4];
#pragma unroll
    for (int i = 0; i < 4; i++) {
      af[i]  = *(const bf16x8*)&a_sm[(wm + i * 16 + l15) * 32 + quad * 8];
      bfb[i] = *(const bf16x8*)&b_sm[(wn + i * 16 + l15) * 32 + quad * 8];
    }
#pragma unroll
    for (int i = 0; i < 4; i++)
#pragma unroll
      for (int j = 0; j < 4; j++)
        acc[i][j] = __builtin_amdgcn_mfma_f32_16x16x32_bf16(af[i], bfb[j], acc[i][j], 0, 0, 0);
  }

#pragma unroll
  for (int i = 0; i < 4; i++) {
#pragma unroll
    for (int j = 0; j < 4; j++) {
#pragma unroll
      for (int r = 0; r < 4; r++) {
        const int row = row0 + wm + i * 16 + quad * 4 + r;
        const int col = col0 + wn + j * 16 + l15;
        const float v = acc[i][j][r];
        if (OUT_BF16)
          ((unsigned short*)Cv)[(size_t)row * N + col] = f2bf(v);
        else
          ((float*)Cv)[(size_t)row * N + col] = v;
      }
    }
  }
}

// ---------------- fused causal attention v10 -------------------------------
// grid (16, NH, B), 256 threads (4 waves). Block A processes q-tile A
// (64 rows, keys 0..A) then q-tile 31-A (keys 0..31-A): 33 rounds for every
// block, every wave active every round (diag tile engages all 4 waves).
// 4-deep LDS buffers, prefetch distance 2, counted vmcnt + raw s_barrier.
// Round t: PV(t-1) || QK^T+softmax+pack(t); phase switch at t = A+1.
__global__ __launch_bounds__(256, 2) void attn_fused10(
    const unsigned short* __restrict__ qkv,
    const unsigned short* __restrict__ vT,
    unsigned short* __restrict__ attnout) {
  const int h = blockIdx.y, b = blockIdx.z;
  const int A = blockIdx.x;                     // q-tile pair (A, 31-A)
  const int tid = threadIdx.x;
  const int lane = tid & 63, wave = tid >> 6;   // wave 0..3
  const int quad = lane >> 4, l15 = lane & 15;
  const int sw = l15 & 7;

  __shared__ __align__(16) unsigned short k_sm[4 * 4096];   // [buf][64 keys][64 d]
  __shared__ __align__(16) unsigned short vt_sm[4 * 4096];  // [buf][64 d][64 keys]

  const int ntA = A + 1;    // rounds in phase A (key tiles 0..A)
  const int NT = 33;        // total rounds: (A+1) + (32-A)

  int qt = A;                                   // current phase's q-tile
  int qrow = qt * 64 + wave * 16 + l15;         // this lane's q row

  // Q fragment (B-operand for S^T, A/B layouts are lane-symmetric)
  bf16x8 qf[2];
  {
    const unsigned short* qp = qkv + (size_t)(b * S_ + qrow) * N3 + h * HD + quad * 8;
    qf[0] = *(const bf16x8*)qp;
    qf[1] = *(const bf16x8*)(qp + 32);
  }

  f32x4 o[4];   // O^T accumulator: d = mb*16+quad*4+r, col = qrow
#pragma unroll
  for (int n = 0; n < 4; n++) o[n] = (f32x4){0.f, 0.f, 0.f, 0.f};
  float lsum = 0.f;

  // staging (R6-verified 256-thread pattern): thread stages rows r0s, r0s+32;
  // phys chunk tid&7 holds logical chunk (tid&7)^(r0s&7) (XOR swizzle)
  const int r0s = tid >> 3;                       // 0..31
  const int gch = ((tid & 7) ^ (r0s & 7)) * 8;
  const unsigned short* kgb = qkv + (size_t)(b * S_ + r0s) * N3 + DM + h * HD + gch;
  const unsigned short* vgb = vT + (size_t)((b * NH + h) * HD + r0s) * S_ + gch;

  // bpermute pull addresses (byte addr = src_lane*4), quad-dim transpose
  const int addrA = (((quad * 2) & 3) * 16 + l15) * 4;
  const int addrB = (((quad * 2 + 1) & 3) * 16 + l15) * 4;

  // stage round w (key tile ktof(w)) into LDS buffer buf
  auto STAGE = [&](int w, int buf) {
    const int ktw = (w < ntA) ? w : (w - ntA);
    const unsigned short* kgt = kgb + (size_t)ktw * 64 * N3;
    const unsigned short* vgt = vgb + ktw * 64;
    gload_lds16(&k_sm[buf * 4096 + tid * 8], kgt);
    gload_lds16(&k_sm[buf * 4096 + tid * 8 + 2048], kgt + (size_t)32 * N3);
    gload_lds16(&vt_sm[buf * 4096 + tid * 8], vgt);
    gload_lds16(&vt_sm[buf * 4096 + tid * 8 + 2048], vgt + (size_t)32 * S_);
  };

  // carried pipeline state: packed P of the previous round + its V buffer
  int pk[4][2];
  const unsigned short* vbp = &vt_sm[0];
  const bool hi = quad >= 2;   // m_src = 2ks + (quad>>1)

  // PV step for the previous round (reads pk + vbp, accumulates o[])
  auto PV = [&]() {
#pragma unroll
    for (int ks = 0; ks < 2; ks++) {
      const int m0 = 2 * ks, m1 = m0 + 1;
      const int f0a = __builtin_amdgcn_ds_bpermute(addrA, pk[m0][0]);
      const int f0b = __builtin_amdgcn_ds_bpermute(addrA, pk[m1][0]);
      const int f1a = __builtin_amdgcn_ds_bpermute(addrA, pk[m0][1]);
      const int f1b = __builtin_amdgcn_ds_bpermute(addrA, pk[m1][1]);
      const int f2a = __builtin_amdgcn_ds_bpermute(addrB, pk[m0][0]);
      const int f2b = __builtin_amdgcn_ds_bpermute(addrB, pk[m1][0]);
      const int f3a = __builtin_amdgcn_ds_bpermute(addrB, pk[m0][1]);
      const int f3b = __builtin_amdgcn_ds_bpermute(addrB, pk[m1][1]);
      i32x4 fr;
      fr.x = hi ? f0b : f0a;
      fr.y = hi ? f1b : f1a;
      fr.z = hi ? f2b : f2a;
      fr.w = hi ? f3b : f3a;
      const bf16x8 pfrag = __builtin_bit_cast(bf16x8, fr);
#pragma unroll
      for (int mb = 0; mb < 4; mb++) {
        const int ro = (mb * 16 + l15) * 64;
        bf16x8 vf = *(const bf16x8*)&vbp[ro + (((ks * 4 + quad) ^ sw) << 3)];
        o[mb] = __builtin_amdgcn_mfma_f32_16x16x32_bf16(vf, pfrag, o[mb], 0, 0, 0);
      }
    }
  };

  // normalize + write current accumulator for q row qr
  auto FLUSH = [&](int qr) {
    float l = lsum;
    l += __shfl_xor(l, 16);
    l += __shfl_xor(l, 32);
    const float inv = 1.0f / l;
    const size_t grow = (size_t)(b * S_ + qr);
#pragma unroll
    for (int mb = 0; mb < 4; mb++) {
      ushort4 w;
      w.x = f2bf(o[mb][0] * inv);
      w.y = f2bf(o[mb][1] * inv);
      w.z = f2bf(o[mb][2] * inv);
      w.w = f2bf(o[mb][3] * inv);
      *(ushort4*)&attnout[grow * DM + h * HD + mb * 16 + quad * 4] = w;
    }
  };

  // prologue: prefetch rounds 0 and 1
  STAGE(0, 0);
  STAGE(1, 1);

  for (int t = 0; t < NT; t++) {
    // drain OWN round-t staging; round-(t+1)'s 4 loads may stay in flight
    if (t + 1 < NT) asm volatile("s_waitcnt vmcnt(4)" ::: "memory");
    else            asm volatile("s_waitcnt vmcnt(0)" ::: "memory");
    __builtin_amdgcn_s_barrier();   // round t staged everywhere; t-2 reads done
    __builtin_amdgcn_sched_barrier(0);
    if (t + 2 < NT) STAGE(t + 2, (t + 2) & 3);

    const unsigned short* kb = &k_sm[(t & 3) * 4096];
    const unsigned short* vb = &vt_sm[(t & 3) * 4096];

    // ---- stream B: PV of round t-1 (independent of stream A) ----
    if (t >= 1) PV();

    // ---- phase switch: tile A's last PV just ran; emit it, load tile B ----
    if (t == ntA) {
      FLUSH(qrow);
#pragma unroll
      for (int n = 0; n < 4; n++) o[n] = (f32x4){0.f, 0.f, 0.f, 0.f};
      lsum = 0.f;
      qt = 31 - A;
      qrow = qt * 64 + wave * 16 + l15;
      const unsigned short* qp = qkv + (size_t)(b * S_ + qrow) * N3 + h * HD + quad * 8;
      qf[0] = *(const bf16x8*)qp;
      qf[1] = *(const bf16x8*)(qp + 32);
    }

    // ---- stream A: S^T(t) + softmax + pack ----
    const int kt = (t < ntA) ? t : (t - ntA);
    f32x4 s[4];
#pragma unroll
    for (int mb = 0; mb < 4; mb++) s[mb] = (f32x4){0.f, 0.f, 0.f, 0.f};
#pragma unroll
    for (int mb = 0; mb < 4; mb++) {
      const int ro = (mb * 16 + l15) * 64;
      bf16x8 kf0 = *(const bf16x8*)&kb[ro + ((quad ^ sw) << 3)];
      bf16x8 kf1 = *(const bf16x8*)&kb[ro + (((4 + quad) ^ sw) << 3)];
      s[mb] = __builtin_amdgcn_mfma_f32_16x16x32_bf16(kf0, qf[0], s[mb], 0, 0, 0);
      s[mb] = __builtin_amdgcn_mfma_f32_16x16x32_bf16(kf1, qf[1], s[mb], 0, 0, 0);
    }

    // P = exp2(S) (scale pre-folded); diag tile (kt==qt) is block-uniform
    if (kt != qt) {
#pragma unroll
      for (int mb = 0; mb < 4; mb++)
#pragma unroll
        for (int r = 0; r < 4; r++)
          s[mb][r] = exp2f(s[mb][r]);
    } else {
      const int kq0 = kt * 64 + quad * 4;
#pragma unroll
      for (int mb = 0; mb < 4; mb++)
#pragma unroll
        for (int r = 0; r < 4; r++) {
          const float e = exp2f(s[mb][r]);
          s[mb][r] = (kq0 + mb * 16 + r <= qrow) ? e : 0.f;
        }
    }
#pragma unroll
    for (int mb = 0; mb < 4; mb++)
      lsum += (s[mb][0] + s[mb][1]) + (s[mb][2] + s[mb][3]);

    // pack to bf16 pairs: pk[mb][x] = keys (mb*16+quad*4+2x, +2x+1)
#pragma unroll
    for (int mb = 0; mb < 4; mb++) {
      const unsigned u0 = __float_as_uint(s[mb][0]) + 0x8000u;
      const unsigned u1 = __float_as_uint(s[mb][1]) + 0x8000u;
      const unsigned u2 = __float_as_uint(s[mb][2]) + 0x8000u;
      const unsigned u3 = __float_as_uint(s[mb][3]) + 0x8000u;
      pk[mb][0] = (int)__builtin_amdgcn_perm(u1, u0, 0x07060302u);
      pk[mb][1] = (int)__builtin_amdgcn_perm(u3, u2, 0x07060302u);
    }
    vbp = vb;   // PV(t) runs next round (or in the epilogue)
  }

  // epilogue: PV of the last round, then emit tile B
  PV();
  asm volatile("s_waitcnt vmcnt(0)" ::: "memory");
  FLUSH(qrow);
}

// ---------------------------------------------------------------------------
extern "C" void kernel_launch(void* const* d_in, const int* in_sizes, int n_in,
                              void* d_out, int out_size, void* d_ws, size_t ws_size,
                              hipStream_t stream) {
  const float* query = (const float*)d_in[0];   // [4096][1024]
  const float* w_in  = (const float*)d_in[1];   // [1024][3072]
  const float* w_out = (const float*)d_in[2];   // [1024][1024]
  float* out = (float*)d_out;                   // [4096][1024] fp32

  char* ws = (char*)d_ws;
  unsigned short* qbf     = (unsigned short*)(ws);                 //  8 MB (dead after gemm1)
  unsigned short* vT      = (unsigned short*)(ws);                 //  8 MB (aliases qbf)
  unsigned short* w_in_t  = (unsigned short*)(ws + 8388608);       //  6 MB [3072][1024]
  unsigned short* w_out_t = (unsigned short*)(ws + 14680064);      //  2 MB [1024][1024]
  unsigned short* qkv     = (unsigned short*)(ws + 16777216);      // 24 MB [4096][3072]
  unsigned short* attn    = (unsigned short*)(ws + 41943040);      //  8 MB [4096][1024]

  // 1. convert query fp32 -> bf16
  f32_to_bf16_vec<<<dim3(M_ * DM / 1024), dim3(256), 0, stream>>>(
      (const float4*)query, qbf, M_ * DM / 4);
  // 2. transpose+convert weights; fold 0.125*log2e into W_in Q-columns
  transpose_f32_bf16<<<dim3(N3 / 32, DM / 32), dim3(32, 8), 0, stream>>>(
      w_in, w_in_t, DM, N3, DM, SCALE_LOG2E);
  transpose_f32_bf16<<<dim3(DM / 32, DM / 32), dim3(32, 8), 0, stream>>>(
      w_out, w_out_t, DM, DM, 0, 1.0f);
  // 3. qkv = query @ W_in   [4096][3072] bf16 (Q slice pre-scaled)
  gemm_abt<1><<<dim3(N3 / 128, M_ / 128), dim3(256), 0, stream>>>(qbf, w_in_t, qkv, M_, N3, DM);
  // 4. vT[b][h][d][s] from qkv V slice (qbf is dead now)
  transpose_v<<<dim3(DM / 32, M_ / 32), dim3(32, 8), 0, stream>>>(qkv, vT);
  // 5. fused causal attention -> attn [4096][1024] bf16
  attn_fused10<<<dim3(16, NH, B_), dim3(256), 0, stream>>>(qkv, vT, attn);
  // 6. out = attn @ W_out   [4096][1024] fp32
  gemm_abt<0><<<dim3(DM / 128, M_ / 128), dim3(256), 0, stream>>>(attn, w_out_t, out, M_, DM, DM);
}

// Round 9
// 198.796 us; speedup vs baseline: 1.0347x; 1.0347x over previous
//
#include <hip/hip_runtime.h>

// ---------------------------------------------------------------------------
// MultiHeadedAttention: B=2, S=2048, Dm=1024, H=16, hd=64
// R12: kill the P-transpose. PV switched to mfma_f32_16x16x16_bf16: its
// B-fragment (keys quad*4+j) is EXACTLY the in-lane S^T output s[ks][j]
// -> all 16 ds_bpermute per wave-round deleted (25% of LDS pipe + the
// constant 2.16M bank-conflict signature + 16 LDS round-trips of latency).
// V^T fragment comes from a re-derived vT layout (built in transpose_v):
// 16B unit = keys {32p+q*4+0..3} u {+16...} for one d -> V reads are linear
// conflict-free ds_read_b128 and V staging is a pure linear copy.
// Everything else byte-identical to R10 (best verified 57.2us): 512 thr,
// (j,31-j) wave pairing, 4-deep LDS buffers, counted vmcnt + raw barrier,
// QK(t) || PV(t-1) pipeline, scale*log2e pre-folded into W_in.
// ---------------------------------------------------------------------------

typedef __bf16 bf16x8 __attribute__((ext_vector_type(8)));
typedef __bf16 bf16x4 __attribute__((ext_vector_type(4)));
typedef short s16x4 __attribute__((ext_vector_type(4)));
typedef float f32x4 __attribute__((ext_vector_type(4)));
typedef int i32x2 __attribute__((ext_vector_type(2)));

#define B_   2
#define S_   2048
#define DM   1024
#define NH   16
#define HD   64
#define N3   3072
#define M_   4096   // B_*S_

// 0.125 (1/sqrt(64)) * log2(e) -- folded into W_in Q-columns on host side
#define SCALE_LOG2E 0.180336884f

__device__ __forceinline__ unsigned short f2bf(float f) {
  unsigned int u = __float_as_uint(f);
  u += 0x7fffu + ((u >> 16) & 1u);   // round-to-nearest-even
  return (unsigned short)(u >> 16);
}

__device__ __forceinline__ void gload_lds16(void* lds, const void* g) {
  __builtin_amdgcn_global_load_lds(
      (__attribute__((address_space(1))) void*)g,
      (__attribute__((address_space(3))) void*)lds, 16, 0, 0);
}

// 16x16x16 bf16 MFMA: builtin name differs across ROCm versions
__device__ __forceinline__ f32x4 mfma16(bf16x4 a, bf16x4 b, f32x4 c) {
#if __has_builtin(__builtin_amdgcn_mfma_f32_16x16x16_bf16)
  return __builtin_amdgcn_mfma_f32_16x16x16_bf16(a, b, c, 0, 0, 0);
#else
  return __builtin_amdgcn_mfma_f32_16x16x16bf16_1k(
      __builtin_bit_cast(s16x4, a), __builtin_bit_cast(s16x4, b), c, 0, 0, 0);
#endif
}

// ---------------- fp32 -> bf16 elementwise (query) -------------------------
__global__ __launch_bounds__(256) void f32_to_bf16_vec(
    const float4* __restrict__ in, unsigned short* __restrict__ out, int n4) {
  int i = blockIdx.x * 256 + threadIdx.x;
  if (i < n4) {
    float4 v = in[i];
    ushort4 o;
    o.x = f2bf(v.x); o.y = f2bf(v.y); o.z = f2bf(v.z); o.w = f2bf(v.w);
    *(ushort4*)(&out[(size_t)i * 4]) = o;
  }
}

// ------- fp32 [R][C] -> bf16 [C][R] transpose (weights), row-scaled --------
__global__ __launch_bounds__(256) void transpose_f32_bf16(
    const float* __restrict__ in, unsigned short* __restrict__ out, int R, int C,
    int scale_rows, float scale) {
  __shared__ float tile[32][33];
  const int tx = threadIdx.x, ty = threadIdx.y;
  const int x = blockIdx.x * 32 + tx;
  const int y0 = blockIdx.y * 32;
#pragma unroll
  for (int j = 0; j < 32; j += 8)
    tile[ty + j][tx] = in[(size_t)(y0 + ty + j) * C + x];
  __syncthreads();
  const int ox = y0 + tx;
  const int oy0 = blockIdx.x * 32;
#pragma unroll
  for (int j = 0; j < 32; j += 8) {
    const int orow = oy0 + ty + j;
    float v = tile[tx][ty + j];
    if (orow < scale_rows) v *= scale;
    out[(size_t)orow * R + ox] = f2bf(v);
  }
}

// --------- V slice of qkv -> vTn PV-fragment layout (bf16) -----------------
// Per (b,h,kt): 8KB block of 512 16B-units. Unit u = p*256 + d*4 + q holds
// V[token = kt*64 + 32p + 16*half + q*4 + j][dim d], j=0..3, half=0..1.
// This is exactly the per-lane A-fragment of mfma_16x16x16 PV, so the attn
// kernel stages it linearly and reads it with conflict-free ds_read_b128.
__global__ __launch_bounds__(256) void transpose_v(
    const unsigned short* __restrict__ qkv, unsigned short* __restrict__ vTn) {
  __shared__ unsigned short tile[64][72];   // [token][dim], 16B-aligned rows
  const int kt = blockIdx.x;   // key tile 0..31
  const int h  = blockIdx.y;
  const int b  = blockIdx.z;
  const int t  = threadIdx.x;  // 0..255
  const int row = t >> 3;          // 0..31
  const int c8  = (t & 7) * 8;     // 0..56
#pragma unroll
  for (int rr = 0; rr < 2; rr++) {
    const int s = row + rr * 32;
    const size_t src = (size_t)(b * S_ + kt * 64 + s) * N3 + 2 * DM + h * HD + c8;
    *(float4*)&tile[s][c8] = *(const float4*)&qkv[src];
  }
  __syncthreads();
  const size_t base = (size_t)((b * NH + h) * 32 + kt) * 4096;
#pragma unroll
  for (int u0 = 0; u0 < 2; u0++) {
    const int u = t + u0 * 256;            // 0..511
    const int p = u >> 8, d = (u >> 2) & 63, q = u & 3;
    const int s0 = 32 * p + q * 4;
    ushort4 w0, w1;
    w0.x = tile[s0 + 0][d];  w0.y = tile[s0 + 1][d];
    w0.z = tile[s0 + 2][d];  w0.w = tile[s0 + 3][d];
    w1.x = tile[s0 + 16][d]; w1.y = tile[s0 + 17][d];
    w1.z = tile[s0 + 18][d]; w1.w = tile[s0 + 19][d];
    *(ushort4*)&vTn[base + (size_t)u * 8]     = w0;
    *(ushort4*)&vTn[base + (size_t)u * 8 + 4] = w1;
  }
}

// ---------------- GEMM: C[M][N] = A[M][K] @ Bt[N][K]^T ---------------------
template <int OUT_BF16>
__global__ __launch_bounds__(256) void gemm_abt(
    const unsigned short* __restrict__ A, const unsigned short* __restrict__ Bt,
    void* __restrict__ Cv, int M, int N, int K) {
  __shared__ __align__(16) unsigned short a_sm[128 * 32];
  __shared__ __align__(16) unsigned short b_sm[128 * 32];
  const int tid = threadIdx.x;
  const int lane = tid & 63, wave = tid >> 6;
  const int quad = lane >> 4, l15 = lane & 15;
  const int row0 = blockIdx.y * 128, col0 = blockIdx.x * 128;
  const int wm = (wave >> 1) * 64, wn = (wave & 1) * 64;

  f32x4 acc[4][4];
#pragma unroll
  for (int i = 0; i < 4; i++)
#pragma unroll
    for (int j = 0; j < 4; j++) acc[i][j] = (f32x4){0.f, 0.f, 0.f, 0.f};

  const int e0 = tid * 8;

  for (int k0 = 0; k0 < K; k0 += 32) {
    __syncthreads();
#pragma unroll
    for (int i = 0; i < 2; i++) {
      int e = e0 + i * 2048;
      int r = e >> 5, c = e & 31;
      gload_lds16(&a_sm[e], &A[(size_t)(row0 + r) * K + k0 + c]);
      gload_lds16(&b_sm[e], &Bt[(size_t)(col0 + r) * K + k0 + c]);
    }
    __syncthreads();

    bf16x8 af[4], bfb[4];
#pragma unroll
    for (int i = 0; i < 4; i++) {
      af[i]  = *(const bf16x8*)&a_sm[(wm + i * 16 + l15) * 32 + quad * 8];
      bfb[i] = *(const bf16x8*)&b_sm[(wn + i * 16 + l15) * 32 + quad * 8];
    }
#pragma unroll
    for (int i = 0; i < 4; i++)
#pragma unroll
      for (int j = 0; j < 4; j++)
        acc[i][j] = __builtin_amdgcn_mfma_f32_16x16x32_bf16(af[i], bfb[j], acc[i][j], 0, 0, 0);
  }

#pragma unroll
  for (int i = 0; i < 4; i++) {
#pragma unroll
    for (int j = 0; j < 4; j++) {
#pragma unroll
      for (int r = 0; r < 4; r++) {
        const int row = row0 + wm + i * 16 + quad * 4 + r;
        const int col = col0 + wn + j * 16 + l15;
        const float v = acc[i][j][r];
        if (OUT_BF16)
          ((unsigned short*)Cv)[(size_t)row * N + col] = f2bf(v);
        else
          ((float*)Cv)[(size_t)row * N + col] = v;
      }
    }
  }
}

// ---------------- fused causal attention v11 -------------------------------
// grid (16, NH, B), 512 threads (8 waves).
// Block j owns q-tiles j (waves 0-3) and 31-j (waves 4-7), 64 rows each.
// 4-deep LDS buffers, prefetch distance 2, counted vmcnt + raw s_barrier.
// Pipeline: iteration t = QK^T+softmax+pack(t) || PV(t-1).
// PV uses mfma_16x16x16: B-frag = in-lane packed s[ks] (no cross-lane ops),
// A-frag = linear conflict-free b128 reads from the vTn fragment layout.
__global__ __launch_bounds__(512, 4) void attn_fused11(
    const unsigned short* __restrict__ qkv,
    const unsigned short* __restrict__ vTn,
    unsigned short* __restrict__ attnout) {
  const int h = blockIdx.y, b = blockIdx.z;
  const int j = blockIdx.x;                     // pair index 0..15
  const int tid = threadIdx.x;
  const int lane = tid & 63, wave = tid >> 6;   // wave 0..7
  const int quad = lane >> 4, l15 = lane & 15;
  const int sw = l15 & 7;

  __shared__ __align__(16) unsigned short k_sm[4 * 4096];   // [buf][64 keys][64 d]
  __shared__ __align__(16) unsigned short vt_sm[4 * 4096];  // [buf][512 x 16B units]

  // wave 0..3 -> low q-tile (rows j*64 ..); wave 4..7 -> high tile ((31-j)*64 ..)
  const int wrow0 = (wave < 4) ? (j * 64 + wave * 16)
                               : ((31 - j) * 64 + (wave - 4) * 16);
  const int qrow = wrow0 + l15;            // this lane's q row (seq-local)

  // Q fragment (B-operand for S^T, A/B layouts are lane-symmetric)
  bf16x8 qf[2];
  {
    const unsigned short* qp = qkv + (size_t)(b * S_ + qrow) * N3 + h * HD + quad * 8;
    qf[0] = *(const bf16x8*)qp;
    qf[1] = *(const bf16x8*)(qp + 32);
  }

  f32x4 o[4];   // O^T accumulator: d = mb*16+quad*4+r, col = qrow
#pragma unroll
  for (int n = 0; n < 4; n++) o[n] = (f32x4){0.f, 0.f, 0.f, 0.f};
  float lsum = 0.f;

  // K staging: thread -> (row r0s, phys chunk tid&7); phys chunk holds logical
  // chunk (tid&7)^(r0s&7) (XOR swizzle, conflict-free b128 reads)
  const int r0s = tid >> 3;                       // 0..63
  const int gch = ((tid & 7) ^ (r0s & 7)) * 8;
  const unsigned short* kgb = qkv + (size_t)(b * S_ + r0s) * N3 + DM + h * HD + gch;
  // V staging: pure linear copy of the pre-arranged fragment layout
  const unsigned short* vgl = vTn + (size_t)((b * NH + h) * 32) * 4096 + tid * 8;

  const int nt = 32 - j;   // key tiles needed by the high q-tile (>= 17)

  // carried pipeline state: packed P of the previous tile + its V buffer
  int pk[4][2];
  const unsigned short* vbp = &vt_sm[0];

  // PV of the previous tile: O^T[d][q] += V^T[d][k] P^T[k][q] via 16x16x16.
  // A-frag: 16B unit (p*256 + (mb*16+l15)*4 + quad); lo half=ks 2p, hi=2p+1.
  // B-frag: pk[ks] = in-lane packed s[ks][0..3] (keys ks*16+quad*4+0..3).
  auto PV = [&]() {
#pragma unroll
    for (int p = 0; p < 2; p++) {
      i32x2 wlo, whi;
      wlo.x = pk[2 * p][0];     wlo.y = pk[2 * p][1];
      whi.x = pk[2 * p + 1][0]; whi.y = pk[2 * p + 1][1];
      const bf16x4 blo = __builtin_bit_cast(bf16x4, wlo);
      const bf16x4 bhi = __builtin_bit_cast(bf16x4, whi);
#pragma unroll
      for (int mb = 0; mb < 4; mb++) {
        const bf16x8 vv =
            *(const bf16x8*)&vbp[(p * 256 + mb * 64 + l15 * 4 + quad) * 8];
        bf16x4 alo, ahi;
#pragma unroll
        for (int i = 0; i < 4; i++) { alo[i] = vv[i]; ahi[i] = vv[i + 4]; }
        o[mb] = mfma16(alo, blo, o[mb]);
        o[mb] = mfma16(ahi, bhi, o[mb]);
      }
    }
  };

  // prologue: prefetch tiles 0 and 1 (each wave: 1 K + 1 V load per tile)
  gload_lds16(&k_sm[tid * 8], kgb);
  gload_lds16(&vt_sm[tid * 8], vgl);
  gload_lds16(&k_sm[4096 + tid * 8], kgb + (size_t)64 * N3);
  gload_lds16(&vt_sm[4096 + tid * 8], vgl + 4096);

  for (int t = 0; t < nt; t++) {
    // wait OWN tile-t staging; tile-(t+1)'s 2 loads may stay in flight
    if (t + 1 < nt) asm volatile("s_waitcnt vmcnt(2)" ::: "memory");
    else            asm volatile("s_waitcnt vmcnt(0)" ::: "memory");
    __builtin_amdgcn_s_barrier();   // tile t staged everywhere; t-2 reads done
    __builtin_amdgcn_sched_barrier(0);
    if (t + 2 < nt) {               // prefetch tile t+2 into buffer (t+2)%4
      const int b2 = (t + 2) & 3;
      gload_lds16(&k_sm[b2 * 4096 + tid * 8], kgb + (size_t)(t + 2) * 64 * N3);
      gload_lds16(&vt_sm[b2 * 4096 + tid * 8], vgl + (size_t)(t + 2) * 4096);
    }
    const unsigned short* kb = &k_sm[(t & 3) * 4096];
    const unsigned short* vb = &vt_sm[(t & 3) * 4096];

    // ---- stream B: PV of tile t-1 (independent of stream A) ----
    if (t >= 1 && (t - 1) * 64 <= wrow0 + 15) PV();

    // ---- stream A: S^T(t) + softmax + pack ----
    if (t * 64 <= wrow0 + 15) {
      f32x4 s[4];
#pragma unroll
      for (int mb = 0; mb < 4; mb++) s[mb] = (f32x4){0.f, 0.f, 0.f, 0.f};
#pragma unroll
      for (int mb = 0; mb < 4; mb++) {
        const int ro = (mb * 16 + l15) * 64;
        bf16x8 kf0 = *(const bf16x8*)&kb[ro + ((quad ^ sw) << 3)];
        bf16x8 kf1 = *(const bf16x8*)&kb[ro + (((4 + quad) ^ sw) << 3)];
        s[mb] = __builtin_amdgcn_mfma_f32_16x16x32_bf16(kf0, qf[0], s[mb], 0, 0, 0);
        s[mb] = __builtin_amdgcn_mfma_f32_16x16x32_bf16(kf1, qf[1], s[mb], 0, 0, 0);
      }

      // P = exp2(S) (scale pre-folded); mask only on the diagonal tile
      if (t * 64 + 63 <= wrow0) {
#pragma unroll
        for (int mb = 0; mb < 4; mb++)
#pragma unroll
          for (int r = 0; r < 4; r++)
            s[mb][r] = exp2f(s[mb][r]);
      } else {
        const int kq0 = t * 64 + quad * 4;
#pragma unroll
        for (int mb = 0; mb < 4; mb++)
#pragma unroll
          for (int r = 0; r < 4; r++) {
            const float e = exp2f(s[mb][r]);
            s[mb][r] = (kq0 + mb * 16 + r <= qrow) ? e : 0.f;
          }
      }
#pragma unroll
      for (int mb = 0; mb < 4; mb++)
        lsum += (s[mb][0] + s[mb][1]) + (s[mb][2] + s[mb][3]);

      // pack to bf16 pairs: pk[ks] = keys (ks*16+quad*4+0..3) = PV B-frag
#pragma unroll
      for (int mb = 0; mb < 4; mb++) {
        const unsigned u0 = __float_as_uint(s[mb][0]) + 0x8000u;
        const unsigned u1 = __float_as_uint(s[mb][1]) + 0x8000u;
        const unsigned u2 = __float_as_uint(s[mb][2]) + 0x8000u;
        const unsigned u3 = __float_as_uint(s[mb][3]) + 0x8000u;
        pk[mb][0] = (int)__builtin_amdgcn_perm(u1, u0, 0x07060302u);
        pk[mb][1] = (int)__builtin_amdgcn_perm(u3, u2, 0x07060302u);
      }
      vbp = vb;   // PV(t) runs next iteration (or in the epilogue)
    }
  }

  // epilogue PV: high-tile waves' last tile (nt-1) was packed, not consumed
  if ((nt - 1) * 64 <= wrow0 + 15) PV();

  // drain any straggler staging writes before workgroup teardown
  asm volatile("s_waitcnt vmcnt(0)" ::: "memory");

  // normalize + write (O^T: lane has 4 consecutive d per mb for its qrow)
  float l = lsum;
  l += __shfl_xor(l, 16);
  l += __shfl_xor(l, 32);
  const float inv = 1.0f / l;
  const size_t grow = (size_t)(b * S_ + qrow);
#pragma unroll
  for (int mb = 0; mb < 4; mb++) {
    ushort4 w;
    w.x = f2bf(o[mb][0] * inv);
    w.y = f2bf(o[mb][1] * inv);
    w.z = f2bf(o[mb][2] * inv);
    w.w = f2bf(o[mb][3] * inv);
    *(ushort4*)&attnout[grow * DM + h * HD + mb * 16 + quad * 4] = w;
  }
}

// ---------------------------------------------------------------------------
extern "C" void kernel_launch(void* const* d_in, const int* in_sizes, int n_in,
                              void* d_out, int out_size, void* d_ws, size_t ws_size,
                              hipStream_t stream) {
  const float* query = (const float*)d_in[0];   // [4096][1024]
  const float* w_in  = (const float*)d_in[1];   // [1024][3072]
  const float* w_out = (const float*)d_in[2];   // [1024][1024]
  float* out = (float*)d_out;                   // [4096][1024] fp32

  char* ws = (char*)d_ws;
  unsigned short* qbf     = (unsigned short*)(ws);                 //  8 MB (dead after gemm1)
  unsigned short* vTn     = (unsigned short*)(ws);                 //  8 MB (aliases qbf)
  unsigned short* w_in_t  = (unsigned short*)(ws + 8388608);       //  6 MB [3072][1024]
  unsigned short* w_out_t = (unsigned short*)(ws + 14680064);      //  2 MB [1024][1024]
  unsigned short* qkv     = (unsigned short*)(ws + 16777216);      // 24 MB [4096][3072]
  unsigned short* attn    = (unsigned short*)(ws + 41943040);      //  8 MB [4096][1024]

  // 1. convert query fp32 -> bf16
  f32_to_bf16_vec<<<dim3(M_ * DM / 1024), dim3(256), 0, stream>>>(
      (const float4*)query, qbf, M_ * DM / 4);
  // 2. transpose+convert weights; fold 0.125*log2e into W_in Q-columns
  transpose_f32_bf16<<<dim3(N3 / 32, DM / 32), dim3(32, 8), 0, stream>>>(
      w_in, w_in_t, DM, N3, DM, SCALE_LOG2E);
  transpose_f32_bf16<<<dim3(DM / 32, DM / 32), dim3(32, 8), 0, stream>>>(
      w_out, w_out_t, DM, DM, 0, 1.0f);
  // 3. qkv = query @ W_in   [4096][3072] bf16 (Q slice pre-scaled)
  gemm_abt<1><<<dim3(N3 / 128, M_ / 128), dim3(256), 0, stream>>>(qbf, w_in_t, qkv, M_, N3, DM);
  // 4. vTn PV-fragment layout from qkv V slice (qbf is dead now)
  transpose_v<<<dim3(32, NH, B_), dim3(256), 0, stream>>>(qkv, vTn);
  // 5. fused causal attention -> attn [4096][1024] bf16
  attn_fused11<<<dim3(16, NH, B_), dim3(512), 0, stream>>>(qkv, vTn, attn);
  // 6. out = attn @ W_out   [4096][1024] fp32
  gemm_abt<0><<<dim3(DM / 128, M_ / 128), dim3(256), 0, stream>>>(attn, w_out_t, out, M_, DM, DM);
}

// Round 10
// 194.603 us; speedup vs baseline: 1.0570x; 1.0215x over previous
//
#include <hip/hip_runtime.h>

// ---------------------------------------------------------------------------
// MultiHeadedAttention: B=2, S=2048, Dm=1024, H=16, hd=64
// R13: attn VALU-cut + gemm2 TLP:
//  - attn pack: v_cvt_pk_bf16_f32 (1 inst per f32-pair, RTNE) replaces the
//    6-op add+perm sequence: 24 -> 8 VALU per round on the S->PV critical path
//  - attn: s_setprio(1) around QK/PV MFMA clusters (T5; phase-diverse waves)
//  - gemm2: 64x128 tile kernel -> grid (8,64)=512 blocks = 2 blocks/CU
//    (old 128x128 grid was 256 = exactly 1/CU: barrier drains fully exposed)
//  - everything else byte-identical to R12 (verified, 52.0us attn)
// ---------------------------------------------------------------------------

typedef __bf16 bf16x8 __attribute__((ext_vector_type(8)));
typedef __bf16 bf16x4 __attribute__((ext_vector_type(4)));
typedef short s16x4 __attribute__((ext_vector_type(4)));
typedef float f32x4 __attribute__((ext_vector_type(4)));
typedef int i32x2 __attribute__((ext_vector_type(2)));

#define B_   2
#define S_   2048
#define DM   1024
#define NH   16
#define HD   64
#define N3   3072
#define M_   4096   // B_*S_

// 0.125 (1/sqrt(64)) * log2(e) -- folded into W_in Q-columns on host side
#define SCALE_LOG2E 0.180336884f

__device__ __forceinline__ unsigned short f2bf(float f) {
  unsigned int u = __float_as_uint(f);
  u += 0x7fffu + ((u >> 16) & 1u);   // round-to-nearest-even
  return (unsigned short)(u >> 16);
}

__device__ __forceinline__ void gload_lds16(void* lds, const void* g) {
  __builtin_amdgcn_global_load_lds(
      (__attribute__((address_space(1))) void*)g,
      (__attribute__((address_space(3))) void*)lds, 16, 0, 0);
}

// 16x16x16 bf16 MFMA: builtin name differs across ROCm versions
__device__ __forceinline__ f32x4 mfma16(bf16x4 a, bf16x4 b, f32x4 c) {
#if __has_builtin(__builtin_amdgcn_mfma_f32_16x16x16_bf16)
  return __builtin_amdgcn_mfma_f32_16x16x16_bf16(a, b, c, 0, 0, 0);
#else
  return __builtin_amdgcn_mfma_f32_16x16x16bf16_1k(
      __builtin_bit_cast(s16x4, a), __builtin_bit_cast(s16x4, b), c, 0, 0, 0);
#endif
}

// packed f32 pair -> bf16x2 in one VALU op (RTNE), lo=s0 hi=s1
__device__ __forceinline__ int cvtpk(float s0, float s1) {
  int r;
  asm("v_cvt_pk_bf16_f32 %0, %1, %2" : "=v"(r) : "v"(s0), "v"(s1));
  return r;
}

// ---------------- fp32 -> bf16 elementwise (query) -------------------------
__global__ __launch_bounds__(256) void f32_to_bf16_vec(
    const float4* __restrict__ in, unsigned short* __restrict__ out, int n4) {
  int i = blockIdx.x * 256 + threadIdx.x;
  if (i < n4) {
    float4 v = in[i];
    ushort4 o;
    o.x = f2bf(v.x); o.y = f2bf(v.y); o.z = f2bf(v.z); o.w = f2bf(v.w);
    *(ushort4*)(&out[(size_t)i * 4]) = o;
  }
}

// ------- fp32 [R][C] -> bf16 [C][R] transpose (weights), row-scaled --------
__global__ __launch_bounds__(256) void transpose_f32_bf16(
    const float* __restrict__ in, unsigned short* __restrict__ out, int R, int C,
    int scale_rows, float scale) {
  __shared__ float tile[32][33];
  const int tx = threadIdx.x, ty = threadIdx.y;
  const int x = blockIdx.x * 32 + tx;
  const int y0 = blockIdx.y * 32;
#pragma unroll
  for (int j = 0; j < 32; j += 8)
    tile[ty + j][tx] = in[(size_t)(y0 + ty + j) * C + x];
  __syncthreads();
  const int ox = y0 + tx;
  const int oy0 = blockIdx.x * 32;
#pragma unroll
  for (int j = 0; j < 32; j += 8) {
    const int orow = oy0 + ty + j;
    float v = tile[tx][ty + j];
    if (orow < scale_rows) v *= scale;
    out[(size_t)orow * R + ox] = f2bf(v);
  }
}

// --------- V slice of qkv -> vTn PV-fragment layout (bf16) -----------------
// Per (b,h,kt): 8KB block of 512 16B-units. Unit u = p*256 + d*4 + q holds
// V[token = kt*64 + 32p + 16*half + q*4 + j][dim d], j=0..3, half=0..1.
__global__ __launch_bounds__(256) void transpose_v(
    const unsigned short* __restrict__ qkv, unsigned short* __restrict__ vTn) {
  __shared__ unsigned short tile[64][72];   // [token][dim], 16B-aligned rows
  const int kt = blockIdx.x;   // key tile 0..31
  const int h  = blockIdx.y;
  const int b  = blockIdx.z;
  const int t  = threadIdx.x;  // 0..255
  const int row = t >> 3;          // 0..31
  const int c8  = (t & 7) * 8;     // 0..56
#pragma unroll
  for (int rr = 0; rr < 2; rr++) {
    const int s = row + rr * 32;
    const size_t src = (size_t)(b * S_ + kt * 64 + s) * N3 + 2 * DM + h * HD + c8;
    *(float4*)&tile[s][c8] = *(const float4*)&qkv[src];
  }
  __syncthreads();
  const size_t base = (size_t)((b * NH + h) * 32 + kt) * 4096;
#pragma unroll
  for (int u0 = 0; u0 < 2; u0++) {
    const int u = t + u0 * 256;            // 0..511
    const int p = u >> 8, d = (u >> 2) & 63, q = u & 3;
    const int s0 = 32 * p + q * 4;
    ushort4 w0, w1;
    w0.x = tile[s0 + 0][d];  w0.y = tile[s0 + 1][d];
    w0.z = tile[s0 + 2][d];  w0.w = tile[s0 + 3][d];
    w1.x = tile[s0 + 16][d]; w1.y = tile[s0 + 17][d];
    w1.z = tile[s0 + 18][d]; w1.w = tile[s0 + 19][d];
    *(ushort4*)&vTn[base + (size_t)u * 8]     = w0;
    *(ushort4*)&vTn[base + (size_t)u * 8 + 4] = w1;
  }
}

// ---------------- GEMM 128x128: C[M][N] = A[M][K] @ Bt[N][K]^T -------------
template <int OUT_BF16>
__global__ __launch_bounds__(256) void gemm_abt(
    const unsigned short* __restrict__ A, const unsigned short* __restrict__ Bt,
    void* __restrict__ Cv, int M, int N, int K) {
  __shared__ __align__(16) unsigned short a_sm[128 * 32];
  __shared__ __align__(16) unsigned short b_sm[128 * 32];
  const int tid = threadIdx.x;
  const int lane = tid & 63, wave = tid >> 6;
  const int quad = lane >> 4, l15 = lane & 15;
  const int row0 = blockIdx.y * 128, col0 = blockIdx.x * 128;
  const int wm = (wave >> 1) * 64, wn = (wave & 1) * 64;

  f32x4 acc[4][4];
#pragma unroll
  for (int i = 0; i < 4; i++)
#pragma unroll
    for (int j = 0; j < 4; j++) acc[i][j] = (f32x4){0.f, 0.f, 0.f, 0.f};

  const int e0 = tid * 8;

  for (int k0 = 0; k0 < K; k0 += 32) {
    __syncthreads();
#pragma unroll
    for (int i = 0; i < 2; i++) {
      int e = e0 + i * 2048;
      int r = e >> 5, c = e & 31;
      gload_lds16(&a_sm[e], &A[(size_t)(row0 + r) * K + k0 + c]);
      gload_lds16(&b_sm[e], &Bt[(size_t)(col0 + r) * K + k0 + c]);
    }
    __syncthreads();

    bf16x8 af[4], bfb[4];
#pragma unroll
    for (int i = 0; i < 4; i++) {
      af[i]  = *(const bf16x8*)&a_sm[(wm + i * 16 + l15) * 32 + quad * 8];
      bfb[i] = *(const bf16x8*)&b_sm[(wn + i * 16 + l15) * 32 + quad * 8];
    }
#pragma unroll
    for (int i = 0; i < 4; i++)
#pragma unroll
      for (int j = 0; j < 4; j++)
        acc[i][j] = __builtin_amdgcn_mfma_f32_16x16x32_bf16(af[i], bfb[j], acc[i][j], 0, 0, 0);
  }

#pragma unroll
  for (int i = 0; i < 4; i++) {
#pragma unroll
    for (int j = 0; j < 4; j++) {
#pragma unroll
      for (int r = 0; r < 4; r++) {
        const int row = row0 + wm + i * 16 + quad * 4 + r;
        const int col = col0 + wn + j * 16 + l15;
        const float v = acc[i][j][r];
        if (OUT_BF16)
          ((unsigned short*)Cv)[(size_t)row * N + col] = f2bf(v);
        else
          ((float*)Cv)[(size_t)row * N + col] = v;
      }
    }
  }
}

// ---------------- GEMM 64x128 (fp32 out): 2 blocks/CU variant --------------
// grid (N/128, M/64), 256 threads. Wave w: rows 0..63, cols w*32..+31.
__global__ __launch_bounds__(256) void gemm_abt_64(
    const unsigned short* __restrict__ A, const unsigned short* __restrict__ Bt,
    float* __restrict__ C, int M, int N, int K) {
  __shared__ __align__(16) unsigned short a_sm[64 * 32];    // 4KB
  __shared__ __align__(16) unsigned short b_sm[128 * 32];   // 8KB
  const int tid = threadIdx.x;
  const int lane = tid & 63, wave = tid >> 6;
  const int quad = lane >> 4, l15 = lane & 15;
  const int row0 = blockIdx.y * 64, col0 = blockIdx.x * 128;
  const int wn = wave * 32;

  f32x4 acc[4][2];
#pragma unroll
  for (int i = 0; i < 4; i++)
#pragma unroll
    for (int j = 0; j < 2; j++) acc[i][j] = (f32x4){0.f, 0.f, 0.f, 0.f};

  const int e0 = tid * 8;

  for (int k0 = 0; k0 < K; k0 += 32) {
    __syncthreads();
    {
      const int r = e0 >> 5, c = e0 & 31;
      gload_lds16(&a_sm[e0], &A[(size_t)(row0 + r) * K + k0 + c]);
    }
#pragma unroll
    for (int i = 0; i < 2; i++) {
      int e = e0 + i * 2048;
      int r = e >> 5, c = e & 31;
      gload_lds16(&b_sm[e], &Bt[(size_t)(col0 + r) * K + k0 + c]);
    }
    __syncthreads();

    bf16x8 af[4], bfb[2];
#pragma unroll
    for (int i = 0; i < 4; i++)
      af[i] = *(const bf16x8*)&a_sm[(i * 16 + l15) * 32 + quad * 8];
#pragma unroll
    for (int j = 0; j < 2; j++)
      bfb[j] = *(const bf16x8*)&b_sm[(wn + j * 16 + l15) * 32 + quad * 8];
#pragma unroll
    for (int i = 0; i < 4; i++)
#pragma unroll
      for (int j = 0; j < 2; j++)
        acc[i][j] = __builtin_amdgcn_mfma_f32_16x16x32_bf16(af[i], bfb[j], acc[i][j], 0, 0, 0);
  }

#pragma unroll
  for (int i = 0; i < 4; i++) {
#pragma unroll
    for (int j = 0; j < 2; j++) {
#pragma unroll
      for (int r = 0; r < 4; r++) {
        const int row = row0 + i * 16 + quad * 4 + r;
        const int col = col0 + wn + j * 16 + l15;
        C[(size_t)row * N + col] = acc[i][j][r];
      }
    }
  }
}

// ---------------- fused causal attention v12 -------------------------------
// grid (16, NH, B), 512 threads (8 waves).
// Block j owns q-tiles j (waves 0-3) and 31-j (waves 4-7), 64 rows each.
// 4-deep LDS buffers, prefetch distance 2, counted vmcnt + raw s_barrier.
// Pipeline: iteration t = QK^T+softmax+pack(t) || PV(t-1).
// PV uses mfma_16x16x16: B-frag = in-lane cvt_pk-packed s[ks]; A-frag =
// linear conflict-free b128 reads from the vTn fragment layout.
__global__ __launch_bounds__(512, 4) void attn_fused12(
    const unsigned short* __restrict__ qkv,
    const unsigned short* __restrict__ vTn,
    unsigned short* __restrict__ attnout) {
  const int h = blockIdx.y, b = blockIdx.z;
  const int j = blockIdx.x;                     // pair index 0..15
  const int tid = threadIdx.x;
  const int lane = tid & 63, wave = tid >> 6;   // wave 0..7
  const int quad = lane >> 4, l15 = lane & 15;
  const int sw = l15 & 7;

  __shared__ __align__(16) unsigned short k_sm[4 * 4096];   // [buf][64 keys][64 d]
  __shared__ __align__(16) unsigned short vt_sm[4 * 4096];  // [buf][512 x 16B units]

  // wave 0..3 -> low q-tile (rows j*64 ..); wave 4..7 -> high tile ((31-j)*64 ..)
  const int wrow0 = (wave < 4) ? (j * 64 + wave * 16)
                               : ((31 - j) * 64 + (wave - 4) * 16);
  const int qrow = wrow0 + l15;            // this lane's q row (seq-local)

  // Q fragment (B-operand for S^T, A/B layouts are lane-symmetric)
  bf16x8 qf[2];
  {
    const unsigned short* qp = qkv + (size_t)(b * S_ + qrow) * N3 + h * HD + quad * 8;
    qf[0] = *(const bf16x8*)qp;
    qf[1] = *(const bf16x8*)(qp + 32);
  }

  f32x4 o[4];   // O^T accumulator: d = mb*16+quad*4+r, col = qrow
#pragma unroll
  for (int n = 0; n < 4; n++) o[n] = (f32x4){0.f, 0.f, 0.f, 0.f};
  float lsum = 0.f;

  // K staging: thread -> (row r0s, phys chunk tid&7); phys chunk holds logical
  // chunk (tid&7)^(r0s&7) (XOR swizzle, conflict-free b128 reads)
  const int r0s = tid >> 3;                       // 0..63
  const int gch = ((tid & 7) ^ (r0s & 7)) * 8;
  const unsigned short* kgb = qkv + (size_t)(b * S_ + r0s) * N3 + DM + h * HD + gch;
  // V staging: pure linear copy of the pre-arranged fragment layout
  const unsigned short* vgl = vTn + (size_t)((b * NH + h) * 32) * 4096 + tid * 8;

  const int nt = 32 - j;   // key tiles needed by the high q-tile (>= 17)

  // carried pipeline state: packed P of the previous tile + its V buffer
  int pk[4][2];
  const unsigned short* vbp = &vt_sm[0];

  // PV of the previous tile: O^T[d][q] += V^T[d][k] P^T[k][q] via 16x16x16.
  auto PV = [&]() {
    __builtin_amdgcn_s_setprio(1);
#pragma unroll
    for (int p = 0; p < 2; p++) {
      i32x2 wlo, whi;
      wlo.x = pk[2 * p][0];     wlo.y = pk[2 * p][1];
      whi.x = pk[2 * p + 1][0]; whi.y = pk[2 * p + 1][1];
      const bf16x4 blo = __builtin_bit_cast(bf16x4, wlo);
      const bf16x4 bhi = __builtin_bit_cast(bf16x4, whi);
#pragma unroll
      for (int mb = 0; mb < 4; mb++) {
        const bf16x8 vv =
            *(const bf16x8*)&vbp[(p * 256 + mb * 64 + l15 * 4 + quad) * 8];
        bf16x4 alo, ahi;
#pragma unroll
        for (int i = 0; i < 4; i++) { alo[i] = vv[i]; ahi[i] = vv[i + 4]; }
        o[mb] = mfma16(alo, blo, o[mb]);
        o[mb] = mfma16(ahi, bhi, o[mb]);
      }
    }
    __builtin_amdgcn_s_setprio(0);
  };

  // prologue: prefetch tiles 0 and 1 (each wave: 1 K + 1 V load per tile)
  gload_lds16(&k_sm[tid * 8], kgb);
  gload_lds16(&vt_sm[tid * 8], vgl);
  gload_lds16(&k_sm[4096 + tid * 8], kgb + (size_t)64 * N3);
  gload_lds16(&vt_sm[4096 + tid * 8], vgl + 4096);

  for (int t = 0; t < nt; t++) {
    // wait OWN tile-t staging; tile-(t+1)'s 2 loads may stay in flight
    if (t + 1 < nt) asm volatile("s_waitcnt vmcnt(2)" ::: "memory");
    else            asm volatile("s_waitcnt vmcnt(0)" ::: "memory");
    __builtin_amdgcn_s_barrier();   // tile t staged everywhere; t-2 reads done
    __builtin_amdgcn_sched_barrier(0);
    if (t + 2 < nt) {               // prefetch tile t+2 into buffer (t+2)%4
      const int b2 = (t + 2) & 3;
      gload_lds16(&k_sm[b2 * 4096 + tid * 8], kgb + (size_t)(t + 2) * 64 * N3);
      gload_lds16(&vt_sm[b2 * 4096 + tid * 8], vgl + (size_t)(t + 2) * 4096);
    }
    const unsigned short* kb = &k_sm[(t & 3) * 4096];
    const unsigned short* vb = &vt_sm[(t & 3) * 4096];

    // ---- stream B: PV of tile t-1 (independent of stream A) ----
    if (t >= 1 && (t - 1) * 64 <= wrow0 + 15) PV();

    // ---- stream A: S^T(t) + softmax + pack ----
    if (t * 64 <= wrow0 + 15) {
      f32x4 s[4];
#pragma unroll
      for (int mb = 0; mb < 4; mb++) s[mb] = (f32x4){0.f, 0.f, 0.f, 0.f};
      __builtin_amdgcn_s_setprio(1);
#pragma unroll
      for (int mb = 0; mb < 4; mb++) {
        const int ro = (mb * 16 + l15) * 64;
        bf16x8 kf0 = *(const bf16x8*)&kb[ro + ((quad ^ sw) << 3)];
        bf16x8 kf1 = *(const bf16x8*)&kb[ro + (((4 + quad) ^ sw) << 3)];
        s[mb] = __builtin_amdgcn_mfma_f32_16x16x32_bf16(kf0, qf[0], s[mb], 0, 0, 0);
        s[mb] = __builtin_amdgcn_mfma_f32_16x16x32_bf16(kf1, qf[1], s[mb], 0, 0, 0);
      }
      __builtin_amdgcn_s_setprio(0);

      // P = exp2(S) (scale pre-folded); mask only on the diagonal tile
      if (t * 64 + 63 <= wrow0) {
#pragma unroll
        for (int mb = 0; mb < 4; mb++)
#pragma unroll
          for (int r = 0; r < 4; r++)
            s[mb][r] = exp2f(s[mb][r]);
      } else {
        const int kq0 = t * 64 + quad * 4;
#pragma unroll
        for (int mb = 0; mb < 4; mb++)
#pragma unroll
          for (int r = 0; r < 4; r++) {
            const float e = exp2f(s[mb][r]);
            s[mb][r] = (kq0 + mb * 16 + r <= qrow) ? e : 0.f;
          }
      }
#pragma unroll
      for (int mb = 0; mb < 4; mb++)
        lsum += (s[mb][0] + s[mb][1]) + (s[mb][2] + s[mb][3]);

      // pack: pk[ks] = keys (ks*16+quad*4+0..3) = PV B-frag (cvt_pk, RTNE)
#pragma unroll
      for (int mb = 0; mb < 4; mb++) {
        pk[mb][0] = cvtpk(s[mb][0], s[mb][1]);
        pk[mb][1] = cvtpk(s[mb][2], s[mb][3]);
      }
      vbp = vb;   // PV(t) runs next iteration (or in the epilogue)
    }
  }

  // epilogue PV: high-tile waves' last tile (nt-1) was packed, not consumed
  if ((nt - 1) * 64 <= wrow0 + 15) PV();

  // drain any straggler staging writes before workgroup teardown
  asm volatile("s_waitcnt vmcnt(0)" ::: "memory");

  // normalize + write (O^T: lane has 4 consecutive d per mb for its qrow)
  float l = lsum;
  l += __shfl_xor(l, 16);
  l += __shfl_xor(l, 32);
  const float inv = 1.0f / l;
  const size_t grow = (size_t)(b * S_ + qrow);
#pragma unroll
  for (int mb = 0; mb < 4; mb++) {
    ushort4 w;
    w.x = f2bf(o[mb][0] * inv);
    w.y = f2bf(o[mb][1] * inv);
    w.z = f2bf(o[mb][2] * inv);
    w.w = f2bf(o[mb][3] * inv);
    *(ushort4*)&attnout[grow * DM + h * HD + mb * 16 + quad * 4] = w;
  }
}

// ---------------------------------------------------------------------------
extern "C" void kernel_launch(void* const* d_in, const int* in_sizes, int n_in,
                              void* d_out, int out_size, void* d_ws, size_t ws_size,
                              hipStream_t stream) {
  const float* query = (const float*)d_in[0];   // [4096][1024]
  const float* w_in  = (const float*)d_in[1];   // [1024][3072]
  const float* w_out = (const float*)d_in[2];   // [1024][1024]
  float* out = (float*)d_out;                   // [4096][1024] fp32

  char* ws = (char*)d_ws;
  unsigned short* qbf     = (unsigned short*)(ws);                 //  8 MB (dead after gemm1)
  unsigned short* vTn     = (unsigned short*)(ws);                 //  8 MB (aliases qbf)
  unsigned short* w_in_t  = (unsigned short*)(ws + 8388608);       //  6 MB [3072][1024]
  unsigned short* w_out_t = (unsigned short*)(ws + 14680064);      //  2 MB [1024][1024]
  unsigned short* qkv     = (unsigned short*)(ws + 16777216);      // 24 MB [4096][3072]
  unsigned short* attn    = (unsigned short*)(ws + 41943040);      //  8 MB [4096][1024]

  // 1. convert query fp32 -> bf16
  f32_to_bf16_vec<<<dim3(M_ * DM / 1024), dim3(256), 0, stream>>>(
      (const float4*)query, qbf, M_ * DM / 4);
  // 2. transpose+convert weights; fold 0.125*log2e into W_in Q-columns
  transpose_f32_bf16<<<dim3(N3 / 32, DM / 32), dim3(32, 8), 0, stream>>>(
      w_in, w_in_t, DM, N3, DM, SCALE_LOG2E);
  transpose_f32_bf16<<<dim3(DM / 32, DM / 32), dim3(32, 8), 0, stream>>>(
      w_out, w_out_t, DM, DM, 0, 1.0f);
  // 3. qkv = query @ W_in   [4096][3072] bf16 (Q slice pre-scaled)
  gemm_abt<1><<<dim3(N3 / 128, M_ / 128), dim3(256), 0, stream>>>(qbf, w_in_t, qkv, M_, N3, DM);
  // 4. vTn PV-fragment layout from qkv V slice (qbf is dead now)
  transpose_v<<<dim3(32, NH, B_), dim3(256), 0, stream>>>(qkv, vTn);
  // 5. fused causal attention -> attn [4096][1024] bf16
  attn_fused12<<<dim3(16, NH, B_), dim3(512), 0, stream>>>(qkv, vTn, attn);
  // 6. out = attn @ W_out   [4096][1024] fp32 (64x128 tiles, 2 blocks/CU)
  gemm_abt_64<<<dim3(DM / 128, M_ / 64), dim3(256), 0, stream>>>(attn, w_out_t, out, M_, DM, DM);
}

// Round 11
// 192.665 us; speedup vs baseline: 1.0676x; 1.0101x over previous
//
#include <hip/hip_runtime.h>

// ---------------------------------------------------------------------------
// MultiHeadedAttention: B=2, S=2048, Dm=1024, H=16, hd=64
// R14: launch-count collapse 7 -> 4 (suspected ~10us/launch overhead = ~70us
// of the constant 145us non-attn residual):
//  - prep: qbf convert + w_in^T(scaled) + w_out^T fused into ONE kernel
//    (task by blockIdx range; block-uniform branches)
//  - gemm1 epilogue writes V-slice (cols>=2048) DIRECTLY in the vTn
//    PV-fragment layout -> transpose_v kernel deleted (and 8MB fewer writes)
//  - workspace re-alias: vTn -> old attn slot (free during gemm1); attn
//    output -> qbf slot (dead after gemm1). Still 48MB.
//  - attn (R13-verified, 49.9us) and gemm2 byte-identical
// ---------------------------------------------------------------------------

typedef __bf16 bf16x8 __attribute__((ext_vector_type(8)));
typedef __bf16 bf16x4 __attribute__((ext_vector_type(4)));
typedef short s16x4 __attribute__((ext_vector_type(4)));
typedef float f32x4 __attribute__((ext_vector_type(4)));
typedef int i32x2 __attribute__((ext_vector_type(2)));

#define B_   2
#define S_   2048
#define DM   1024
#define NH   16
#define HD   64
#define N3   3072
#define M_   4096   // B_*S_

// 0.125 (1/sqrt(64)) * log2(e) -- folded into W_in Q-columns on host side
#define SCALE_LOG2E 0.180336884f

__device__ __forceinline__ unsigned short f2bf(float f) {
  unsigned int u = __float_as_uint(f);
  u += 0x7fffu + ((u >> 16) & 1u);   // round-to-nearest-even
  return (unsigned short)(u >> 16);
}

__device__ __forceinline__ void gload_lds16(void* lds, const void* g) {
  __builtin_amdgcn_global_load_lds(
      (__attribute__((address_space(1))) void*)g,
      (__attribute__((address_space(3))) void*)lds, 16, 0, 0);
}

// 16x16x16 bf16 MFMA: builtin name differs across ROCm versions
__device__ __forceinline__ f32x4 mfma16(bf16x4 a, bf16x4 b, f32x4 c) {
#if __has_builtin(__builtin_amdgcn_mfma_f32_16x16x16_bf16)
  return __builtin_amdgcn_mfma_f32_16x16x16_bf16(a, b, c, 0, 0, 0);
#else
  return __builtin_amdgcn_mfma_f32_16x16x16bf16_1k(
      __builtin_bit_cast(s16x4, a), __builtin_bit_cast(s16x4, b), c, 0, 0, 0);
#endif
}

// packed f32 pair -> bf16x2 in one VALU op (RTNE), lo=s0 hi=s1
__device__ __forceinline__ int cvtpk(float s0, float s1) {
  int r;
  asm("v_cvt_pk_bf16_f32 %0, %1, %2" : "=v"(r) : "v"(s0), "v"(s1));
  return r;
}

// ---------------- prep: qbf convert + both weight transposes ---------------
// grid 8192 x 256thr: [0,4096) qbf; [4096,7168) w_in^T (scaled); rest w_out^T
__global__ __launch_bounds__(256) void prep(
    const float* __restrict__ query, const float* __restrict__ w_in,
    const float* __restrict__ w_out, unsigned short* __restrict__ qbf,
    unsigned short* __restrict__ w_in_t, unsigned short* __restrict__ w_out_t) {
  __shared__ float tile[32][33];
  const int bx = blockIdx.x;
  const int t = threadIdx.x;
  if (bx < 4096) {                       // query f32 -> bf16, 1024 elems/block
    const int i = bx * 256 + t;
    const float4 v = ((const float4*)query)[i];
    ushort4 o;
    o.x = f2bf(v.x); o.y = f2bf(v.y); o.z = f2bf(v.z); o.w = f2bf(v.w);
    *(ushort4*)(&qbf[(size_t)i * 4]) = o;
    return;
  }
  // 32x32 transpose tasks (tx = t&31, ty = t>>5; 8 rows per pass)
  const int tx = t & 31, ty = t >> 5;
  const float* in;
  unsigned short* out;
  int R, C, bxx, bxy, scale_rows;
  if (bx < 4096 + 3072) {                // w_in [1024][3072] -> [3072][1024]
    const int id = bx - 4096;
    in = w_in; out = w_in_t; R = DM; C = N3;
    bxx = id % 96; bxy = id / 96; scale_rows = DM;
  } else {                               // w_out [1024][1024] -> [1024][1024]
    const int id = bx - 7168;
    in = w_out; out = w_out_t; R = DM; C = DM;
    bxx = id & 31; bxy = id >> 5; scale_rows = 0;
  }
  const int x = bxx * 32 + tx;
  const int y0 = bxy * 32;
#pragma unroll
  for (int j = 0; j < 32; j += 8)
    tile[ty + j][tx] = in[(size_t)(y0 + ty + j) * C + x];
  __syncthreads();
  const int ox = y0 + tx;
  const int oy0 = bxx * 32;
#pragma unroll
  for (int j = 0; j < 32; j += 8) {
    const int orow = oy0 + ty + j;
    float v = tile[tx][ty + j];
    if (orow < scale_rows) v *= SCALE_LOG2E;
    out[(size_t)orow * R + ox] = f2bf(v);
  }
}

// ------- GEMM1: qkv = A @ Bt^T; V-slice written in vTn fragment layout -----
// C cols [0,2048) -> qkv row-major bf16 (Q,K). Cols [2048,3072) -> vTn:
// per (b,h,kt) 8KB block; unit u = p*256 + d*4 + q holds
// V[token kt*64+32p+16*half+q*4+j][dim d] j=0..3 at elem u*8+half*4.
__global__ __launch_bounds__(256) void gemm_qkv(
    const unsigned short* __restrict__ A, const unsigned short* __restrict__ Bt,
    unsigned short* __restrict__ qkv, unsigned short* __restrict__ vTn) {
  __shared__ __align__(16) unsigned short a_sm[128 * 32];
  __shared__ __align__(16) unsigned short b_sm[128 * 32];
  const int tid = threadIdx.x;
  const int lane = tid & 63, wave = tid >> 6;
  const int quad = lane >> 4, l15 = lane & 15;
  const int row0 = blockIdx.y * 128, col0 = blockIdx.x * 128;
  const int wm = (wave >> 1) * 64, wn = (wave & 1) * 64;
  const int K = DM;

  f32x4 acc[4][4];
#pragma unroll
  for (int i = 0; i < 4; i++)
#pragma unroll
    for (int j = 0; j < 4; j++) acc[i][j] = (f32x4){0.f, 0.f, 0.f, 0.f};

  const int e0 = tid * 8;

  for (int k0 = 0; k0 < K; k0 += 32) {
    __syncthreads();
#pragma unroll
    for (int i = 0; i < 2; i++) {
      int e = e0 + i * 2048;
      int r = e >> 5, c = e & 31;
      gload_lds16(&a_sm[e], &A[(size_t)(row0 + r) * K + k0 + c]);
      gload_lds16(&b_sm[e], &Bt[(size_t)(col0 + r) * K + k0 + c]);
    }
    __syncthreads();

    bf16x8 af[4], bfb[4];
#pragma unroll
    for (int i = 0; i < 4; i++) {
      af[i]  = *(const bf16x8*)&a_sm[(wm + i * 16 + l15) * 32 + quad * 8];
      bfb[i] = *(const bf16x8*)&b_sm[(wn + i * 16 + l15) * 32 + quad * 8];
    }
#pragma unroll
    for (int i = 0; i < 4; i++)
#pragma unroll
      for (int j = 0; j < 4; j++)
        acc[i][j] = __builtin_amdgcn_mfma_f32_16x16x32_bf16(af[i], bfb[j], acc[i][j], 0, 0, 0);
  }

  if (col0 + wn < 2 * DM) {
    // Q/K slices: row-major bf16 into qkv (unchanged from R13)
#pragma unroll
    for (int i = 0; i < 4; i++) {
#pragma unroll
      for (int j = 0; j < 4; j++) {
#pragma unroll
        for (int r = 0; r < 4; r++) {
          const int row = row0 + wm + i * 16 + quad * 4 + r;
          const int col = col0 + wn + j * 16 + l15;
          qkv[(size_t)row * N3 + col] = f2bf(acc[i][j][r]);
        }
      }
    }
  } else {
    // V slice: write vTn fragment layout directly (one ushort4 per (i,j))
    const int head = (col0 + wn - 2 * DM) >> 6;   // wave-uniform
#pragma unroll
    for (int i = 0; i < 4; i++) {
      const int row = row0 + wm + i * 16 + quad * 4;   // token of r=0
      const int b = row >> 11;
      const int srow = row & 2047;
      const int kt = srow >> 6;
      const int s = srow & 63;
      const int p = s >> 5, half = (s >> 4) & 1, q = (s >> 2) & 3;
      const size_t base = (size_t)((b * NH + head) * 32 + kt) * 4096;
#pragma unroll
      for (int j = 0; j < 4; j++) {
        const int d = j * 16 + l15;
        ushort4 w;
        w.x = f2bf(acc[i][j][0]);
        w.y = f2bf(acc[i][j][1]);
        w.z = f2bf(acc[i][j][2]);
        w.w = f2bf(acc[i][j][3]);
        *(ushort4*)&vTn[base + (size_t)(p * 256 + d * 4 + q) * 8 + half * 4] = w;
      }
    }
  }
}

// ---------------- GEMM 64x128 (fp32 out): 2 blocks/CU variant --------------
// grid (N/128, M/64), 256 threads. Wave w: rows 0..63, cols w*32..+31.
__global__ __launch_bounds__(256) void gemm_abt_64(
    const unsigned short* __restrict__ A, const unsigned short* __restrict__ Bt,
    float* __restrict__ C, int M, int N, int K) {
  __shared__ __align__(16) unsigned short a_sm[64 * 32];    // 4KB
  __shared__ __align__(16) unsigned short b_sm[128 * 32];   // 8KB
  const int tid = threadIdx.x;
  const int lane = tid & 63, wave = tid >> 6;
  const int quad = lane >> 4, l15 = lane & 15;
  const int row0 = blockIdx.y * 64, col0 = blockIdx.x * 128;
  const int wn = wave * 32;

  f32x4 acc[4][2];
#pragma unroll
  for (int i = 0; i < 4; i++)
#pragma unroll
    for (int j = 0; j < 2; j++) acc[i][j] = (f32x4){0.f, 0.f, 0.f, 0.f};

  const int e0 = tid * 8;

  for (int k0 = 0; k0 < K; k0 += 32) {
    __syncthreads();
    {
      const int r = e0 >> 5, c = e0 & 31;
      gload_lds16(&a_sm[e0], &A[(size_t)(row0 + r) * K + k0 + c]);
    }
#pragma unroll
    for (int i = 0; i < 2; i++) {
      int e = e0 + i * 2048;
      int r = e >> 5, c = e & 31;
      gload_lds16(&b_sm[e], &Bt[(size_t)(col0 + r) * K + k0 + c]);
    }
    __syncthreads();

    bf16x8 af[4], bfb[2];
#pragma unroll
    for (int i = 0; i < 4; i++)
      af[i] = *(const bf16x8*)&a_sm[(i * 16 + l15) * 32 + quad * 8];
#pragma unroll
    for (int j = 0; j < 2; j++)
      bfb[j] = *(const bf16x8*)&b_sm[(wn + j * 16 + l15) * 32 + quad * 8];
#pragma unroll
    for (int i = 0; i < 4; i++)
#pragma unroll
      for (int j = 0; j < 2; j++)
        acc[i][j] = __builtin_amdgcn_mfma_f32_16x16x32_bf16(af[i], bfb[j], acc[i][j], 0, 0, 0);
  }

#pragma unroll
  for (int i = 0; i < 4; i++) {
#pragma unroll
    for (int j = 0; j < 2; j++) {
#pragma unroll
      for (int r = 0; r < 4; r++) {
        const int row = row0 + i * 16 + quad * 4 + r;
        const int col = col0 + wn + j * 16 + l15;
        C[(size_t)row * N + col] = acc[i][j][r];
      }
    }
  }
}

// ---------------- fused causal attention v12 (R13-verified) ----------------
// grid (16, NH, B), 512 threads (8 waves).
// Block j owns q-tiles j (waves 0-3) and 31-j (waves 4-7), 64 rows each.
// 4-deep LDS buffers, prefetch distance 2, counted vmcnt + raw s_barrier.
// Pipeline: iteration t = QK^T+softmax+pack(t) || PV(t-1).
// PV uses mfma_16x16x16: B-frag = in-lane cvt_pk-packed s[ks]; A-frag =
// linear conflict-free b128 reads from the vTn fragment layout.
__global__ __launch_bounds__(512, 4) void attn_fused12(
    const unsigned short* __restrict__ qkv,
    const unsigned short* __restrict__ vTn,
    unsigned short* __restrict__ attnout) {
  const int h = blockIdx.y, b = blockIdx.z;
  const int j = blockIdx.x;                     // pair index 0..15
  const int tid = threadIdx.x;
  const int lane = tid & 63, wave = tid >> 6;   // wave 0..7
  const int quad = lane >> 4, l15 = lane & 15;
  const int sw = l15 & 7;

  __shared__ __align__(16) unsigned short k_sm[4 * 4096];   // [buf][64 keys][64 d]
  __shared__ __align__(16) unsigned short vt_sm[4 * 4096];  // [buf][512 x 16B units]

  // wave 0..3 -> low q-tile (rows j*64 ..); wave 4..7 -> high tile ((31-j)*64 ..)
  const int wrow0 = (wave < 4) ? (j * 64 + wave * 16)
                               : ((31 - j) * 64 + (wave - 4) * 16);
  const int qrow = wrow0 + l15;            // this lane's q row (seq-local)

  // Q fragment (B-operand for S^T, A/B layouts are lane-symmetric)
  bf16x8 qf[2];
  {
    const unsigned short* qp = qkv + (size_t)(b * S_ + qrow) * N3 + h * HD + quad * 8;
    qf[0] = *(const bf16x8*)qp;
    qf[1] = *(const bf16x8*)(qp + 32);
  }

  f32x4 o[4];   // O^T accumulator: d = mb*16+quad*4+r, col = qrow
#pragma unroll
  for (int n = 0; n < 4; n++) o[n] = (f32x4){0.f, 0.f, 0.f, 0.f};
  float lsum = 0.f;

  // K staging: thread -> (row r0s, phys chunk tid&7); phys chunk holds logical
  // chunk (tid&7)^(r0s&7) (XOR swizzle, conflict-free b128 reads)
  const int r0s = tid >> 3;                       // 0..63
  const int gch = ((tid & 7) ^ (r0s & 7)) * 8;
  const unsigned short* kgb = qkv + (size_t)(b * S_ + r0s) * N3 + DM + h * HD + gch;
  // V staging: pure linear copy of the pre-arranged fragment layout
  const unsigned short* vgl = vTn + (size_t)((b * NH + h) * 32) * 4096 + tid * 8;

  const int nt = 32 - j;   // key tiles needed by the high q-tile (>= 17)

  // carried pipeline state: packed P of the previous tile + its V buffer
  int pk[4][2];
  const unsigned short* vbp = &vt_sm[0];

  // PV of the previous tile: O^T[d][q] += V^T[d][k] P^T[k][q] via 16x16x16.
  auto PV = [&]() {
    __builtin_amdgcn_s_setprio(1);
#pragma unroll
    for (int p = 0; p < 2; p++) {
      i32x2 wlo, whi;
      wlo.x = pk[2 * p][0];     wlo.y = pk[2 * p][1];
      whi.x = pk[2 * p + 1][0]; whi.y = pk[2 * p + 1][1];
      const bf16x4 blo = __builtin_bit_cast(bf16x4, wlo);
      const bf16x4 bhi = __builtin_bit_cast(bf16x4, whi);
#pragma unroll
      for (int mb = 0; mb < 4; mb++) {
        const bf16x8 vv =
            *(const bf16x8*)&vbp[(p * 256 + mb * 64 + l15 * 4 + quad) * 8];
        bf16x4 alo, ahi;
#pragma unroll
        for (int i = 0; i < 4; i++) { alo[i] = vv[i]; ahi[i] = vv[i + 4]; }
        o[mb] = mfma16(alo, blo, o[mb]);
        o[mb] = mfma16(ahi, bhi, o[mb]);
      }
    }
    __builtin_amdgcn_s_setprio(0);
  };

  // prologue: prefetch tiles 0 and 1 (each wave: 1 K + 1 V load per tile)
  gload_lds16(&k_sm[tid * 8], kgb);
  gload_lds16(&vt_sm[tid * 8], vgl);
  gload_lds16(&k_sm[4096 + tid * 8], kgb + (size_t)64 * N3);
  gload_lds16(&vt_sm[4096 + tid * 8], vgl + 4096);

  for (int t = 0; t < nt; t++) {
    // wait OWN tile-t staging; tile-(t+1)'s 2 loads may stay in flight
    if (t + 1 < nt) asm volatile("s_waitcnt vmcnt(2)" ::: "memory");
    else            asm volatile("s_waitcnt vmcnt(0)" ::: "memory");
    __builtin_amdgcn_s_barrier();   // tile t staged everywhere; t-2 reads done
    __builtin_amdgcn_sched_barrier(0);
    if (t + 2 < nt) {               // prefetch tile t+2 into buffer (t+2)%4
      const int b2 = (t + 2) & 3;
      gload_lds16(&k_sm[b2 * 4096 + tid * 8], kgb + (size_t)(t + 2) * 64 * N3);
      gload_lds16(&vt_sm[b2 * 4096 + tid * 8], vgl + (size_t)(t + 2) * 4096);
    }
    const unsigned short* kb = &k_sm[(t & 3) * 4096];
    const unsigned short* vb = &vt_sm[(t & 3) * 4096];

    // ---- stream B: PV of tile t-1 (independent of stream A) ----
    if (t >= 1 && (t - 1) * 64 <= wrow0 + 15) PV();

    // ---- stream A: S^T(t) + softmax + pack ----
    if (t * 64 <= wrow0 + 15) {
      f32x4 s[4];
#pragma unroll
      for (int mb = 0; mb < 4; mb++) s[mb] = (f32x4){0.f, 0.f, 0.f, 0.f};
      __builtin_amdgcn_s_setprio(1);
#pragma unroll
      for (int mb = 0; mb < 4; mb++) {
        const int ro = (mb * 16 + l15) * 64;
        bf16x8 kf0 = *(const bf16x8*)&kb[ro + ((quad ^ sw) << 3)];
        bf16x8 kf1 = *(const bf16x8*)&kb[ro + (((4 + quad) ^ sw) << 3)];
        s[mb] = __builtin_amdgcn_mfma_f32_16x16x32_bf16(kf0, qf[0], s[mb], 0, 0, 0);
        s[mb] = __builtin_amdgcn_mfma_f32_16x16x32_bf16(kf1, qf[1], s[mb], 0, 0, 0);
      }
      __builtin_amdgcn_s_setprio(0);

      // P = exp2(S) (scale pre-folded); mask only on the diagonal tile
      if (t * 64 + 63 <= wrow0) {
#pragma unroll
        for (int mb = 0; mb < 4; mb++)
#pragma unroll
          for (int r = 0; r < 4; r++)
            s[mb][r] = exp2f(s[mb][r]);
      } else {
        const int kq0 = t * 64 + quad * 4;
#pragma unroll
        for (int mb = 0; mb < 4; mb++)
#pragma unroll
          for (int r = 0; r < 4; r++) {
            const float e = exp2f(s[mb][r]);
            s[mb][r] = (kq0 + mb * 16 + r <= qrow) ? e : 0.f;
          }
      }
#pragma unroll
      for (int mb = 0; mb < 4; mb++)
        lsum += (s[mb][0] + s[mb][1]) + (s[mb][2] + s[mb][3]);

      // pack: pk[ks] = keys (ks*16+quad*4+0..3) = PV B-frag (cvt_pk, RTNE)
#pragma unroll
      for (int mb = 0; mb < 4; mb++) {
        pk[mb][0] = cvtpk(s[mb][0], s[mb][1]);
        pk[mb][1] = cvtpk(s[mb][2], s[mb][3]);
      }
      vbp = vb;   // PV(t) runs next iteration (or in the epilogue)
    }
  }

  // epilogue PV: high-tile waves' last tile (nt-1) was packed, not consumed
  if ((nt - 1) * 64 <= wrow0 + 15) PV();

  // drain any straggler staging writes before workgroup teardown
  asm volatile("s_waitcnt vmcnt(0)" ::: "memory");

  // normalize + write (O^T: lane has 4 consecutive d per mb for its qrow)
  float l = lsum;
  l += __shfl_xor(l, 16);
  l += __shfl_xor(l, 32);
  const float inv = 1.0f / l;
  const size_t grow = (size_t)(b * S_ + qrow);
#pragma unroll
  for (int mb = 0; mb < 4; mb++) {
    ushort4 w;
    w.x = f2bf(o[mb][0] * inv);
    w.y = f2bf(o[mb][1] * inv);
    w.z = f2bf(o[mb][2] * inv);
    w.w = f2bf(o[mb][3] * inv);
    *(ushort4*)&attnout[grow * DM + h * HD + mb * 16 + quad * 4] = w;
  }
}

// ---------------------------------------------------------------------------
extern "C" void kernel_launch(void* const* d_in, const int* in_sizes, int n_in,
                              void* d_out, int out_size, void* d_ws, size_t ws_size,
                              hipStream_t stream) {
  const float* query = (const float*)d_in[0];   // [4096][1024]
  const float* w_in  = (const float*)d_in[1];   // [1024][3072]
  const float* w_out = (const float*)d_in[2];   // [1024][1024]
  float* out = (float*)d_out;                   // [4096][1024] fp32

  char* ws = (char*)d_ws;
  // lifetimes: qbf prep->gemm1; w_in_t prep->gemm1; w_out_t prep->gemm2;
  // qkv(Q,K) gemm1->attn; vTn gemm1->attn; attnout attn->gemm2.
  unsigned short* qbf     = (unsigned short*)(ws);                 // 8 MB
  unsigned short* attn    = (unsigned short*)(ws);                 // 8 MB (aliases qbf, dead after gemm1)
  unsigned short* w_in_t  = (unsigned short*)(ws + 8388608);       // 6 MB [3072][1024]
  unsigned short* w_out_t = (unsigned short*)(ws + 14680064);      // 2 MB [1024][1024]
  unsigned short* qkv     = (unsigned short*)(ws + 16777216);      // 24 MB [4096][3072] (V third unused)
  unsigned short* vTn     = (unsigned short*)(ws + 41943040);      // 8 MB PV-fragment layout

  // 1. prep: query->bf16, w_in^T (Q-cols pre-scaled by 0.125*log2e), w_out^T
  prep<<<dim3(8192), dim3(256), 0, stream>>>(query, w_in, w_out, qbf, w_in_t, w_out_t);
  // 2. qkv = query @ W_in; V slice written directly in vTn fragment layout
  gemm_qkv<<<dim3(N3 / 128, M_ / 128), dim3(256), 0, stream>>>(qbf, w_in_t, qkv, vTn);
  // 3. fused causal attention -> attn [4096][1024] bf16
  attn_fused12<<<dim3(16, NH, B_), dim3(512), 0, stream>>>(qkv, vTn, attn);
  // 4. out = attn @ W_out   [4096][1024] fp32 (64x128 tiles, 2 blocks/CU)
  gemm_abt_64<<<dim3(DM / 128, M_ / 64), dim3(256), 0, stream>>>(attn, w_out_t, out, M_, DM, DM);
}

// Round 12
// 189.376 us; speedup vs baseline: 1.0862x; 1.0174x over previous
//
#include <hip/hip_runtime.h>

// ---------------------------------------------------------------------------
// MultiHeadedAttention: B=2, S=2048, Dm=1024, H=16, hd=64
// R15: attn staging-locality + round-halving (base: R13/R14 verified body):
//  - T1 chunked XCD swizzle: block p -> lg=(p&7)*64+(p>>3); each XCD then
//    holds 4 heads x 1 batch = 2MB KV -> L2-resident staging
//  - KVBLK=128: two 64-key sub-tiles per barrier round (sub-tile compute
//    verbatim from R13; PV runs in-round, no cross-barrier carry).
//    Barriers 33 -> ~17/block; vmcnt(0)+s_barrier per round (R9: counted
//    vs drain was null here); staging prefetch distance = 1 round.
//  - prep / gemm_qkv / gemm_abt_64 byte-identical to R14
// ---------------------------------------------------------------------------

typedef __bf16 bf16x8 __attribute__((ext_vector_type(8)));
typedef __bf16 bf16x4 __attribute__((ext_vector_type(4)));
typedef short s16x4 __attribute__((ext_vector_type(4)));
typedef float f32x4 __attribute__((ext_vector_type(4)));
typedef int i32x2 __attribute__((ext_vector_type(2)));

#define B_   2
#define S_   2048
#define DM   1024
#define NH   16
#define HD   64
#define N3   3072
#define M_   4096   // B_*S_

// 0.125 (1/sqrt(64)) * log2(e) -- folded into W_in Q-columns on host side
#define SCALE_LOG2E 0.180336884f

__device__ __forceinline__ unsigned short f2bf(float f) {
  unsigned int u = __float_as_uint(f);
  u += 0x7fffu + ((u >> 16) & 1u);   // round-to-nearest-even
  return (unsigned short)(u >> 16);
}

__device__ __forceinline__ void gload_lds16(void* lds, const void* g) {
  __builtin_amdgcn_global_load_lds(
      (__attribute__((address_space(1))) void*)g,
      (__attribute__((address_space(3))) void*)lds, 16, 0, 0);
}

// 16x16x16 bf16 MFMA: builtin name differs across ROCm versions
__device__ __forceinline__ f32x4 mfma16(bf16x4 a, bf16x4 b, f32x4 c) {
#if __has_builtin(__builtin_amdgcn_mfma_f32_16x16x16_bf16)
  return __builtin_amdgcn_mfma_f32_16x16x16_bf16(a, b, c, 0, 0, 0);
#else
  return __builtin_amdgcn_mfma_f32_16x16x16bf16_1k(
      __builtin_bit_cast(s16x4, a), __builtin_bit_cast(s16x4, b), c, 0, 0, 0);
#endif
}

// packed f32 pair -> bf16x2 in one VALU op (RTNE), lo=s0 hi=s1
__device__ __forceinline__ int cvtpk(float s0, float s1) {
  int r;
  asm("v_cvt_pk_bf16_f32 %0, %1, %2" : "=v"(r) : "v"(s0), "v"(s1));
  return r;
}

// ---------------- prep: qbf convert + both weight transposes ---------------
// grid 8192 x 256thr: [0,4096) qbf; [4096,7168) w_in^T (scaled); rest w_out^T
__global__ __launch_bounds__(256) void prep(
    const float* __restrict__ query, const float* __restrict__ w_in,
    const float* __restrict__ w_out, unsigned short* __restrict__ qbf,
    unsigned short* __restrict__ w_in_t, unsigned short* __restrict__ w_out_t) {
  __shared__ float tile[32][33];
  const int bx = blockIdx.x;
  const int t = threadIdx.x;
  if (bx < 4096) {                       // query f32 -> bf16, 1024 elems/block
    const int i = bx * 256 + t;
    const float4 v = ((const float4*)query)[i];
    ushort4 o;
    o.x = f2bf(v.x); o.y = f2bf(v.y); o.z = f2bf(v.z); o.w = f2bf(v.w);
    *(ushort4*)(&qbf[(size_t)i * 4]) = o;
    return;
  }
  // 32x32 transpose tasks (tx = t&31, ty = t>>5; 8 rows per pass)
  const int tx = t & 31, ty = t >> 5;
  const float* in;
  unsigned short* out;
  int R, C, bxx, bxy, scale_rows;
  if (bx < 4096 + 3072) {                // w_in [1024][3072] -> [3072][1024]
    const int id = bx - 4096;
    in = w_in; out = w_in_t; R = DM; C = N3;
    bxx = id % 96; bxy = id / 96; scale_rows = DM;
  } else {                               // w_out [1024][1024] -> [1024][1024]
    const int id = bx - 7168;
    in = w_out; out = w_out_t; R = DM; C = DM;
    bxx = id & 31; bxy = id >> 5; scale_rows = 0;
  }
  const int x = bxx * 32 + tx;
  const int y0 = bxy * 32;
#pragma unroll
  for (int j = 0; j < 32; j += 8)
    tile[ty + j][tx] = in[(size_t)(y0 + ty + j) * C + x];
  __syncthreads();
  const int ox = y0 + tx;
  const int oy0 = bxx * 32;
#pragma unroll
  for (int j = 0; j < 32; j += 8) {
    const int orow = oy0 + ty + j;
    float v = tile[tx][ty + j];
    if (orow < scale_rows) v *= SCALE_LOG2E;
    out[(size_t)orow * R + ox] = f2bf(v);
  }
}

// ------- GEMM1: qkv = A @ Bt^T; V-slice written in vTn fragment layout -----
// C cols [0,2048) -> qkv row-major bf16 (Q,K). Cols [2048,3072) -> vTn:
// per (b,h,kt) 8KB block; unit u = p*256 + d*4 + q holds
// V[token kt*64+32p+16*half+q*4+j][dim d] j=0..3 at elem u*8+half*4.
__global__ __launch_bounds__(256) void gemm_qkv(
    const unsigned short* __restrict__ A, const unsigned short* __restrict__ Bt,
    unsigned short* __restrict__ qkv, unsigned short* __restrict__ vTn) {
  __shared__ __align__(16) unsigned short a_sm[128 * 32];
  __shared__ __align__(16) unsigned short b_sm[128 * 32];
  const int tid = threadIdx.x;
  const int lane = tid & 63, wave = tid >> 6;
  const int quad = lane >> 4, l15 = lane & 15;
  const int row0 = blockIdx.y * 128, col0 = blockIdx.x * 128;
  const int wm = (wave >> 1) * 64, wn = (wave & 1) * 64;
  const int K = DM;

  f32x4 acc[4][4];
#pragma unroll
  for (int i = 0; i < 4; i++)
#pragma unroll
    for (int j = 0; j < 4; j++) acc[i][j] = (f32x4){0.f, 0.f, 0.f, 0.f};

  const int e0 = tid * 8;

  for (int k0 = 0; k0 < K; k0 += 32) {
    __syncthreads();
#pragma unroll
    for (int i = 0; i < 2; i++) {
      int e = e0 + i * 2048;
      int r = e >> 5, c = e & 31;
      gload_lds16(&a_sm[e], &A[(size_t)(row0 + r) * K + k0 + c]);
      gload_lds16(&b_sm[e], &Bt[(size_t)(col0 + r) * K + k0 + c]);
    }
    __syncthreads();

    bf16x8 af[4], bfb[4];
#pragma unroll
    for (int i = 0; i < 4; i++) {
      af[i]  = *(const bf16x8*)&a_sm[(wm + i * 16 + l15) * 32 + quad * 8];
      bfb[i] = *(const bf16x8*)&b_sm[(wn + i * 16 + l15) * 32 + quad * 8];
    }
#pragma unroll
    for (int i = 0; i < 4; i++)
#pragma unroll
      for (int j = 0; j < 4; j++)
        acc[i][j] = __builtin_amdgcn_mfma_f32_16x16x32_bf16(af[i], bfb[j], acc[i][j], 0, 0, 0);
  }

  if (col0 + wn < 2 * DM) {
    // Q/K slices: row-major bf16 into qkv
#pragma unroll
    for (int i = 0; i < 4; i++) {
#pragma unroll
      for (int j = 0; j < 4; j++) {
#pragma unroll
        for (int r = 0; r < 4; r++) {
          const int row = row0 + wm + i * 16 + quad * 4 + r;
          const int col = col0 + wn + j * 16 + l15;
          qkv[(size_t)row * N3 + col] = f2bf(acc[i][j][r]);
        }
      }
    }
  } else {
    // V slice: write vTn fragment layout directly (one ushort4 per (i,j))
    const int head = (col0 + wn - 2 * DM) >> 6;   // wave-uniform
#pragma unroll
    for (int i = 0; i < 4; i++) {
      const int row = row0 + wm + i * 16 + quad * 4;   // token of r=0
      const int b = row >> 11;
      const int srow = row & 2047;
      const int kt = srow >> 6;
      const int s = srow & 63;
      const int p = s >> 5, half = (s >> 4) & 1, q = (s >> 2) & 3;
      const size_t base = (size_t)((b * NH + head) * 32 + kt) * 4096;
#pragma unroll
      for (int j = 0; j < 4; j++) {
        const int d = j * 16 + l15;
        ushort4 w;
        w.x = f2bf(acc[i][j][0]);
        w.y = f2bf(acc[i][j][1]);
        w.z = f2bf(acc[i][j][2]);
        w.w = f2bf(acc[i][j][3]);
        *(ushort4*)&vTn[base + (size_t)(p * 256 + d * 4 + q) * 8 + half * 4] = w;
      }
    }
  }
}

// ---------------- GEMM 64x128 (fp32 out): 2 blocks/CU variant --------------
// grid (N/128, M/64), 256 threads. Wave w: rows 0..63, cols w*32..+31.
__global__ __launch_bounds__(256) void gemm_abt_64(
    const unsigned short* __restrict__ A, const unsigned short* __restrict__ Bt,
    float* __restrict__ C, int M, int N, int K) {
  __shared__ __align__(16) unsigned short a_sm[64 * 32];    // 4KB
  __shared__ __align__(16) unsigned short b_sm[128 * 32];   // 8KB
  const int tid = threadIdx.x;
  const int lane = tid & 63, wave = tid >> 6;
  const int quad = lane >> 4, l15 = lane & 15;
  const int row0 = blockIdx.y * 64, col0 = blockIdx.x * 128;
  const int wn = wave * 32;

  f32x4 acc[4][2];
#pragma unroll
  for (int i = 0; i < 4; i++)
#pragma unroll
    for (int j = 0; j < 2; j++) acc[i][j] = (f32x4){0.f, 0.f, 0.f, 0.f};

  const int e0 = tid * 8;

  for (int k0 = 0; k0 < K; k0 += 32) {
    __syncthreads();
    {
      const int r = e0 >> 5, c = e0 & 31;
      gload_lds16(&a_sm[e0], &A[(size_t)(row0 + r) * K + k0 + c]);
    }
#pragma unroll
    for (int i = 0; i < 2; i++) {
      int e = e0 + i * 2048;
      int r = e >> 5, c = e & 31;
      gload_lds16(&b_sm[e], &Bt[(size_t)(col0 + r) * K + k0 + c]);
    }
    __syncthreads();

    bf16x8 af[4], bfb[2];
#pragma unroll
    for (int i = 0; i < 4; i++)
      af[i] = *(const bf16x8*)&a_sm[(i * 16 + l15) * 32 + quad * 8];
#pragma unroll
    for (int j = 0; j < 2; j++)
      bfb[j] = *(const bf16x8*)&b_sm[(wn + j * 16 + l15) * 32 + quad * 8];
#pragma unroll
    for (int i = 0; i < 4; i++)
#pragma unroll
      for (int j = 0; j < 2; j++)
        acc[i][j] = __builtin_amdgcn_mfma_f32_16x16x32_bf16(af[i], bfb[j], acc[i][j], 0, 0, 0);
  }

#pragma unroll
  for (int i = 0; i < 4; i++) {
#pragma unroll
    for (int j = 0; j < 2; j++) {
#pragma unroll
      for (int r = 0; r < 4; r++) {
        const int row = row0 + i * 16 + quad * 4 + r;
        const int col = col0 + wn + j * 16 + l15;
        C[(size_t)row * N + col] = acc[i][j][r];
      }
    }
  }
}

// ---------------- fused causal attention v13 -------------------------------
// grid (16, NH, B) = 512 blocks, 512 threads (8 waves).
// T1 chunked XCD swizzle: physical flat id p -> logical lg=(p&7)*64+(p>>3);
// each XCD then runs 4 heads x 1 batch (2MB KV, L2-fit).
// Block (logical j) owns q-tiles j (waves 0-3) and 31-j (waves 4-7).
// KVBLK=128 rounds: two 64-key sub-tiles per barrier; 4 LDS buffers;
// staging prefetch distance 1 round; vmcnt(0) + raw s_barrier per round.
// Sub-tile body (QK 16x16x32, exp2, cvt_pk pack, PV 16x16x16) = R13 verbatim.
__global__ __launch_bounds__(512, 4) void attn_fused13(
    const unsigned short* __restrict__ qkv,
    const unsigned short* __restrict__ vTn,
    unsigned short* __restrict__ attnout) {
  // chunked XCD swizzle (bijective: 512 blocks = 8 XCD x 64)
  const int p = blockIdx.x + (blockIdx.y << 4) + (blockIdx.z << 8);
  const int lg = ((p & 7) << 6) + (p >> 3);
  const int j = lg & 15;
  const int h = (lg >> 4) & 15;
  const int b = lg >> 8;

  const int tid = threadIdx.x;
  const int lane = tid & 63, wave = tid >> 6;   // wave 0..7
  const int quad = lane >> 4, l15 = lane & 15;
  const int sw = l15 & 7;

  __shared__ __align__(16) unsigned short k_sm[4 * 4096];   // [buf][64 keys][64 d]
  __shared__ __align__(16) unsigned short vt_sm[4 * 4096];  // [buf][512 x 16B units]

  // wave 0..3 -> low q-tile (rows j*64 ..); wave 4..7 -> high tile ((31-j)*64 ..)
  const int wrow0 = (wave < 4) ? (j * 64 + wave * 16)
                               : ((31 - j) * 64 + (wave - 4) * 16);
  const int qrow = wrow0 + l15;            // this lane's q row (seq-local)

  // Q fragment (B-operand for S^T, A/B layouts are lane-symmetric)
  bf16x8 qf[2];
  {
    const unsigned short* qp = qkv + (size_t)(b * S_ + qrow) * N3 + h * HD + quad * 8;
    qf[0] = *(const bf16x8*)qp;
    qf[1] = *(const bf16x8*)(qp + 32);
  }

  f32x4 o[4];   // O^T accumulator: d = mb*16+quad*4+r, col = qrow
#pragma unroll
  for (int n = 0; n < 4; n++) o[n] = (f32x4){0.f, 0.f, 0.f, 0.f};
  float lsum = 0.f;

  // K staging: thread -> (row r0s, phys chunk tid&7); phys chunk holds logical
  // chunk (tid&7)^(r0s&7) (XOR swizzle, conflict-free b128 reads)
  const int r0s = tid >> 3;                       // 0..63
  const int gch = ((tid & 7) ^ (r0s & 7)) * 8;
  const unsigned short* kgb = qkv + (size_t)(b * S_ + r0s) * N3 + DM + h * HD + gch;
  // V staging: pure linear copy of the pre-arranged fragment layout
  const unsigned short* vgl = vTn + (size_t)((b * NH + h) * 32) * 4096 + tid * 8;

  const int nt = 32 - j;            // key tiles needed by the high q-tile
  const int nR = (nt + 1) >> 1;     // 128-key rounds

  // stage 64-key tile t into buffer t&3 (2 loads/thread)
  auto STAGE = [&](int t) {
    const int bu = (t & 3) * 4096;
    gload_lds16(&k_sm[bu + tid * 8], kgb + (size_t)t * 64 * N3);
    gload_lds16(&vt_sm[bu + tid * 8], vgl + (size_t)t * 4096);
  };

  // one 64-key sub-tile: QK^T + softmax + pack + PV (R13-verified body)
  auto SUBTILE = [&](int t) {
    const unsigned short* kb = &k_sm[(t & 3) * 4096];
    const unsigned short* vb = &vt_sm[(t & 3) * 4096];

    f32x4 s[4];
#pragma unroll
    for (int mb = 0; mb < 4; mb++) s[mb] = (f32x4){0.f, 0.f, 0.f, 0.f};
    __builtin_amdgcn_s_setprio(1);
#pragma unroll
    for (int mb = 0; mb < 4; mb++) {
      const int ro = (mb * 16 + l15) * 64;
      bf16x8 kf0 = *(const bf16x8*)&kb[ro + ((quad ^ sw) << 3)];
      bf16x8 kf1 = *(const bf16x8*)&kb[ro + (((4 + quad) ^ sw) << 3)];
      s[mb] = __builtin_amdgcn_mfma_f32_16x16x32_bf16(kf0, qf[0], s[mb], 0, 0, 0);
      s[mb] = __builtin_amdgcn_mfma_f32_16x16x32_bf16(kf1, qf[1], s[mb], 0, 0, 0);
    }
    __builtin_amdgcn_s_setprio(0);

    // P = exp2(S) (scale pre-folded); mask only on the diagonal tile
    if (t * 64 + 63 <= wrow0) {
#pragma unroll
      for (int mb = 0; mb < 4; mb++)
#pragma unroll
        for (int r = 0; r < 4; r++)
          s[mb][r] = exp2f(s[mb][r]);
    } else {
      const int kq0 = t * 64 + quad * 4;
#pragma unroll
      for (int mb = 0; mb < 4; mb++)
#pragma unroll
        for (int r = 0; r < 4; r++) {
          const float e = exp2f(s[mb][r]);
          s[mb][r] = (kq0 + mb * 16 + r <= qrow) ? e : 0.f;
        }
    }
#pragma unroll
    for (int mb = 0; mb < 4; mb++)
      lsum += (s[mb][0] + s[mb][1]) + (s[mb][2] + s[mb][3]);

    // pack: pk[ks] = keys (ks*16+quad*4+0..3) = PV B-frag (cvt_pk, RTNE)
    int pk[4][2];
#pragma unroll
    for (int mb = 0; mb < 4; mb++) {
      pk[mb][0] = cvtpk(s[mb][0], s[mb][1]);
      pk[mb][1] = cvtpk(s[mb][2], s[mb][3]);
    }

    // PV: O^T[d][q] += V^T[d][k] P^T[k][q] via 16x16x16
    __builtin_amdgcn_s_setprio(1);
#pragma unroll
    for (int pp = 0; pp < 2; pp++) {
      i32x2 wlo, whi;
      wlo.x = pk[2 * pp][0];     wlo.y = pk[2 * pp][1];
      whi.x = pk[2 * pp + 1][0]; whi.y = pk[2 * pp + 1][1];
      const bf16x4 blo = __builtin_bit_cast(bf16x4, wlo);
      const bf16x4 bhi = __builtin_bit_cast(bf16x4, whi);
#pragma unroll
      for (int mb = 0; mb < 4; mb++) {
        const bf16x8 vv =
            *(const bf16x8*)&vb[(pp * 256 + mb * 64 + l15 * 4 + quad) * 8];
        bf16x4 alo, ahi;
#pragma unroll
        for (int i = 0; i < 4; i++) { alo[i] = vv[i]; ahi[i] = vv[i + 4]; }
        o[mb] = mfma16(alo, blo, o[mb]);
        o[mb] = mfma16(ahi, bhi, o[mb]);
      }
    }
    __builtin_amdgcn_s_setprio(0);
  };

  // prologue: stage round 0 (tiles 0,1)
  STAGE(0);
  if (1 < nt) STAGE(1);

  for (int r = 0; r < nR; r++) {
    const int t0 = 2 * r, t1 = 2 * r + 1;
    // own staging for this round complete; barrier publishes all waves'
    asm volatile("s_waitcnt vmcnt(0)" ::: "memory");
    __builtin_amdgcn_s_barrier();
    __builtin_amdgcn_sched_barrier(0);
    // prefetch round r+1 (buffers (t0+2)&3,(t1+2)&3 — disjoint from t0,t1)
    if (r + 1 < nR) {
      STAGE(t0 + 2);
      if (t1 + 2 < nt) STAGE(t1 + 2);
    }
    // two independent sub-tiles per round (ILP across their chains)
    if (t0 * 64 <= wrow0 + 15) SUBTILE(t0);
    if (t1 < nt && t1 * 64 <= wrow0 + 15) SUBTILE(t1);
  }

  // drain any straggler staging writes before workgroup teardown
  asm volatile("s_waitcnt vmcnt(0)" ::: "memory");

  // normalize + write (O^T: lane has 4 consecutive d per mb for its qrow)
  float l = lsum;
  l += __shfl_xor(l, 16);
  l += __shfl_xor(l, 32);
  const float inv = 1.0f / l;
  const size_t grow = (size_t)(b * S_ + qrow);
#pragma unroll
  for (int mb = 0; mb < 4; mb++) {
    ushort4 w;
    w.x = f2bf(o[mb][0] * inv);
    w.y = f2bf(o[mb][1] * inv);
    w.z = f2bf(o[mb][2] * inv);
    w.w = f2bf(o[mb][3] * inv);
    *(ushort4*)&attnout[grow * DM + h * HD + mb * 16 + quad * 4] = w;
  }
}

// ---------------------------------------------------------------------------
extern "C" void kernel_launch(void* const* d_in, const int* in_sizes, int n_in,
                              void* d_out, int out_size, void* d_ws, size_t ws_size,
                              hipStream_t stream) {
  const float* query = (const float*)d_in[0];   // [4096][1024]
  const float* w_in  = (const float*)d_in[1];   // [1024][3072]
  const float* w_out = (const float*)d_in[2];   // [1024][1024]
  float* out = (float*)d_out;                   // [4096][1024] fp32

  char* ws = (char*)d_ws;
  // lifetimes: qbf prep->gemm1; w_in_t prep->gemm1; w_out_t prep->gemm2;
  // qkv(Q,K) gemm1->attn; vTn gemm1->attn; attnout attn->gemm2.
  unsigned short* qbf     = (unsigned short*)(ws);                 // 8 MB
  unsigned short* attn    = (unsigned short*)(ws);                 // 8 MB (aliases qbf, dead after gemm1)
  unsigned short* w_in_t  = (unsigned short*)(ws + 8388608);       // 6 MB [3072][1024]
  unsigned short* w_out_t = (unsigned short*)(ws + 14680064);      // 2 MB [1024][1024]
  unsigned short* qkv     = (unsigned short*)(ws + 16777216);      // 24 MB [4096][3072] (V third unused)
  unsigned short* vTn     = (unsigned short*)(ws + 41943040);      // 8 MB PV-fragment layout

  // 1. prep: query->bf16, w_in^T (Q-cols pre-scaled by 0.125*log2e), w_out^T
  prep<<<dim3(8192), dim3(256), 0, stream>>>(query, w_in, w_out, qbf, w_in_t, w_out_t);
  // 2. qkv = query @ W_in; V slice written directly in vTn fragment layout
  gemm_qkv<<<dim3(N3 / 128, M_ / 128), dim3(256), 0, stream>>>(qbf, w_in_t, qkv, vTn);
  // 3. fused causal attention -> attn [4096][1024] bf16
  attn_fused13<<<dim3(16, NH, B_), dim3(512), 0, stream>>>(qkv, vTn, attn);
  // 4. out = attn @ W_out   [4096][1024] fp32 (64x128 tiles, 2 blocks/CU)
  gemm_abt_64<<<dim3(DM / 128, M_ / 64), dim3(256), 0, stream>>>(attn, w_out_t, out, M_, DM, DM);
}